// Round 2
// baseline (1343.078 us; speedup 1.0000x reference)
//
#include <hip/hip_runtime.h>
#include <hip/hip_bf16.h>
#include <math.h>

#define BD 8
#define HH 56
#define WW 56
#define CC 384
#define HEADS 12
#define HD 32
#define WS 7
#define SS 3
#define NTOK 49
#define NWIN 64            // windows per image (8x8)
#define TOKENS (BD*HH*WW)  // 25088
#define HID 1536
#define TPI (HH*WW)        // tokens per image: 3136

// ---------------- LayerNorm (optionally fused with shift+window-partition gather) ----------------
template<bool SHIFT>
__global__ __launch_bounds__(128)
void ln_kernel(const float* __restrict__ in, const float* __restrict__ g,
               const float* __restrict__ beta, float* __restrict__ out)
{
    int m = blockIdx.x;              // output row (window-ordered if SHIFT)
    const float* src;
    float* dst = out + (size_t)m * CC;
    if (SHIFT) {
        int b  = m / (NWIN * NTOK);
        int rr = m % (NWIN * NTOK);
        int w  = rr / NTOK;          // wh*8+ww
        int t  = rr % NTOK;          // i*7+j
        int wh = w >> 3, ww = w & 7;
        int ti = t / 7,  tj = t - (t / 7) * 7;
        int hh = wh * WS + ti + SS;  if (hh >= HH) hh -= HH;
        int w2 = ww * WS + tj + SS;  if (w2 >= WW) w2 -= WW;
        src = in + ((size_t)b * TPI + hh * WW + w2) * CC;
    } else {
        src = in + (size_t)m * CC;
    }
    int tid = threadIdx.x;
    float v0 = src[tid], v1 = src[tid + 128], v2 = src[tid + 256];
    float s  = v0 + v1 + v2;
    float ss = v0*v0 + v1*v1 + v2*v2;
    #pragma unroll
    for (int off = 32; off > 0; off >>= 1) {
        s  += __shfl_down(s, off);
        ss += __shfl_down(ss, off);
    }
    __shared__ float red[4];
    int wid = tid >> 6, lane = tid & 63;
    if (lane == 0) { red[wid] = s; red[wid + 2] = ss; }
    __syncthreads();
    float tot   = red[0] + red[1];
    float totss = red[2] + red[3];
    float mu   = tot * (1.0f / CC);
    float var  = totss * (1.0f / CC) - mu * mu;
    float rstd = rsqrtf(var + 1e-5f);
    dst[tid]       = (v0 - mu) * rstd * g[tid]       + beta[tid];
    dst[tid + 128] = (v1 - mu) * rstd * g[tid + 128] + beta[tid + 128];
    dst[tid + 256] = (v2 - mu) * rstd * g[tid + 256] + beta[tid + 256];
}

// ---------------- Tiled fp32 GEMM, 128x128x8, 8x8 microtile, compile-time epilogue ----------------
#define EPI_BIAS 0   // out = A@B + bias                     (qkv)
#define EPI_GELU 1   // out = gelu(A@B + bias)               (fc1)
#define EPI_PROJ 2   // xr[pix] = x[pix] + A@B + bias        (proj + window-reverse + roll + residual)
#define EPI_FC2  3   // dout = xr + A@B + bias               (fc2 + residual)

template<int EPI>
__global__ __launch_bounds__(256)
void gemm128(const float* __restrict__ A, const float* __restrict__ Bw,
             const float* __restrict__ bias, const float* __restrict__ extra,
             float* __restrict__ out, int M, int N, int K)
{
    constexpr int BM = 128, BN = 128, BK = 8;
    __shared__ float As[BK][BM + 8];
    __shared__ float Bs[BK][BN];
    int tid = threadIdx.x;
    int tm = tid >> 4;                 // 0..15
    int tn = tid & 15;                 // 0..15
    int m0 = blockIdx.y * BM;
    int n0 = blockIdx.x * BN;
    float acc[8][8] = {};

    for (int k0 = 0; k0 < K; k0 += BK) {
        {   // A tile: 128 rows x 8 cols, transposed into As[k][m]
            int r = tid >> 1;
            int c = (tid & 1) * 4;
            const float4 av = *(const float4*)&A[(size_t)(m0 + r) * K + k0 + c];
            As[c + 0][r] = av.x; As[c + 1][r] = av.y;
            As[c + 2][r] = av.z; As[c + 3][r] = av.w;
        }
        {   // B tile: 8 rows x 128 cols
            int r = tid >> 5;
            int c = (tid & 31) * 4;
            *(float4*)&Bs[r][c] = *(const float4*)&Bw[(size_t)(k0 + r) * N + n0 + c];
        }
        __syncthreads();
        #pragma unroll
        for (int k = 0; k < BK; k++) {
            float a[8], b[8];
            *(float4*)&a[0] = *(const float4*)&As[k][tm * 8];
            *(float4*)&a[4] = *(const float4*)&As[k][tm * 8 + 4];
            *(float4*)&b[0] = *(const float4*)&Bs[k][tn * 8];
            *(float4*)&b[4] = *(const float4*)&Bs[k][tn * 8 + 4];
            #pragma unroll
            for (int i = 0; i < 8; i++)
                #pragma unroll
                for (int j = 0; j < 8; j++)
                    acc[i][j] += a[i] * b[j];
        }
        __syncthreads();
    }

    int nb = n0 + tn * 8;
    float bv[8];
    #pragma unroll
    for (int j = 0; j < 8; j++) bv[j] = bias[nb + j];

    #pragma unroll
    for (int i = 0; i < 8; i++) {
        int mg = m0 + tm * 8 + i;
        if (EPI == EPI_BIAS) {
            float4 o0, o1;
            o0.x = acc[i][0] + bv[0]; o0.y = acc[i][1] + bv[1];
            o0.z = acc[i][2] + bv[2]; o0.w = acc[i][3] + bv[3];
            o1.x = acc[i][4] + bv[4]; o1.y = acc[i][5] + bv[5];
            o1.z = acc[i][6] + bv[6]; o1.w = acc[i][7] + bv[7];
            *(float4*)&out[(size_t)mg * N + nb]     = o0;
            *(float4*)&out[(size_t)mg * N + nb + 4] = o1;
        } else if (EPI == EPI_GELU) {
            float4 o0, o1;
            float v[8];
            #pragma unroll
            for (int j = 0; j < 8; j++) {
                float t = acc[i][j] + bv[j];
                v[j] = 0.5f * t * (1.0f + erff(t * 0.70710678118654752f));
            }
            o0.x = v[0]; o0.y = v[1]; o0.z = v[2]; o0.w = v[3];
            o1.x = v[4]; o1.y = v[5]; o1.z = v[6]; o1.w = v[7];
            *(float4*)&out[(size_t)mg * N + nb]     = o0;
            *(float4*)&out[(size_t)mg * N + nb + 4] = o1;
        } else if (EPI == EPI_PROJ) {
            // window row -> pixel (window reverse + roll(+3,+3)); xr = x + proj_out
            int b  = mg / (NWIN * NTOK);
            int rr = mg % (NWIN * NTOK);
            int w  = rr / NTOK;
            int t  = rr % NTOK;
            int wh = w >> 3, ww = w & 7;
            int ti = t / 7,  tj = t - (t / 7) * 7;
            int hh = wh * WS + ti + SS;  if (hh >= HH) hh -= HH;
            int w2 = ww * WS + tj + SS;  if (w2 >= WW) w2 -= WW;
            size_t pix = (size_t)b * TPI + hh * WW + w2;
            const float* xin = extra + pix * CC + nb;
            float* xo = out + pix * CC + nb;
            float4 x0 = *(const float4*)&xin[0];
            float4 x1 = *(const float4*)&xin[4];
            float4 o0, o1;
            o0.x = x0.x + acc[i][0] + bv[0]; o0.y = x0.y + acc[i][1] + bv[1];
            o0.z = x0.z + acc[i][2] + bv[2]; o0.w = x0.w + acc[i][3] + bv[3];
            o1.x = x1.x + acc[i][4] + bv[4]; o1.y = x1.y + acc[i][5] + bv[5];
            o1.z = x1.z + acc[i][6] + bv[6]; o1.w = x1.w + acc[i][7] + bv[7];
            *(float4*)&xo[0] = o0;
            *(float4*)&xo[4] = o1;
        } else { // EPI_FC2
            const float* xr = extra + (size_t)mg * N + nb;
            float4 x0 = *(const float4*)&xr[0];
            float4 x1 = *(const float4*)&xr[4];
            float4 o0, o1;
            o0.x = x0.x + acc[i][0] + bv[0]; o0.y = x0.y + acc[i][1] + bv[1];
            o0.z = x0.z + acc[i][2] + bv[2]; o0.w = x0.w + acc[i][3] + bv[3];
            o1.x = x1.x + acc[i][4] + bv[4]; o1.y = x1.y + acc[i][5] + bv[5];
            o1.z = x1.z + acc[i][6] + bv[6]; o1.w = x1.w + acc[i][7] + bv[7];
            *(float4*)&out[(size_t)mg * N + nb]     = o0;
            *(float4*)&out[(size_t)mg * N + nb + 4] = o1;
        }
    }
}

// ---------------- Windowed attention: one block per (window, head) within a chunk ----------------
// qkv: chunk-local [gq*NWIN*NTOK, 1152]; out: global att buffer; win0: first global window of chunk
__global__ __launch_bounds__(256)
void attn_kernel(const float* __restrict__ qkv, const float* __restrict__ amask,
                 const float* __restrict__ rpb, float* __restrict__ out, int win0)
{
    int bid  = blockIdx.x;
    int head = bid % HEADS;
    int winl = bid / HEADS;            // chunk-local window
    int wing = win0 + winl;            // global window
    int wl   = wing & (NWIN - 1);      // mask index
    int qbase = winl * NTOK;           // chunk-local token row
    int obase = wing * NTOK;           // global token row

    __shared__ float Q[NTOK][HD + 1];
    __shared__ float Kk[NTOK][HD + 1];
    __shared__ float V[NTOK][HD + 1];
    __shared__ float S[NTOK][52];

    int tid = threadIdx.x;
    const float scale = 0.17677669529663687f;  // 1/sqrt(32)

    for (int idx = tid; idx < NTOK * HD; idx += 256) {
        int t = idx >> 5, d = idx & 31;
        size_t row = (size_t)(qbase + t) * (3 * CC) + head * HD + d;
        Q[t][d]  = qkv[row] * scale;
        Kk[t][d] = qkv[row + CC];
        V[t][d]  = qkv[row + 2 * CC];
    }
    __syncthreads();

    for (int idx = tid; idx < NTOK * NTOK; idx += 256) {
        int i = idx / NTOK, j = idx % NTOK;
        float acc = 0.0f;
        #pragma unroll
        for (int d = 0; d < HD; d++) acc += Q[i][d] * Kk[j][d];
        int yi = i / 7, xi = i - yi * 7;
        int yj = j / 7, xj = j - yj * 7;
        int rel = (yi - yj + WS - 1) * (2 * WS - 1) + (xi - xj + WS - 1);
        acc += rpb[rel * HEADS + head];
        acc += amask[((size_t)wl * NTOK + i) * NTOK + j];
        S[i][j] = acc;
    }
    __syncthreads();

    if (tid < NTOK) {
        float mx = -1e30f;
        #pragma unroll 7
        for (int j = 0; j < NTOK; j++) mx = fmaxf(mx, S[tid][j]);
        float sum = 0.0f;
        #pragma unroll 7
        for (int j = 0; j < NTOK; j++) { float e = __expf(S[tid][j] - mx); S[tid][j] = e; sum += e; }
        float inv = 1.0f / sum;
        #pragma unroll 7
        for (int j = 0; j < NTOK; j++) S[tid][j] *= inv;
    }
    __syncthreads();

    for (int idx = tid; idx < NTOK * HD; idx += 256) {
        int t = idx >> 5, d = idx & 31;
        float acc = 0.0f;
        #pragma unroll
        for (int j = 0; j < NTOK; j++) acc += S[t][j] * V[j][d];
        out[(size_t)(obase + t) * CC + head * HD + d] = acc;
    }
}

// ---------------- launcher ----------------
extern "C" void kernel_launch(void* const* d_in, const int* in_sizes, int n_in,
                              void* d_out, int out_size, void* d_ws, size_t ws_size,
                              hipStream_t stream)
{
    const float* x      = (const float*)d_in[0];
    const float* amask  = (const float*)d_in[1];
    const float* qkv_w  = (const float*)d_in[2];
    const float* qkv_b  = (const float*)d_in[3];
    const float* proj_w = (const float*)d_in[4];
    const float* proj_b = (const float*)d_in[5];
    const float* rpb    = (const float*)d_in[6];
    const float* n1g    = (const float*)d_in[7];
    const float* n1b    = (const float*)d_in[8];
    const float* n2g    = (const float*)d_in[9];
    const float* n2b    = (const float*)d_in[10];
    const float* fc1w   = (const float*)d_in[11];
    const float* fc1b   = (const float*)d_in[12];
    const float* fc2w   = (const float*)d_in[13];
    const float* fc2b   = (const float*)d_in[14];

    float* xr   = (float*)d_out;                  // d_out doubles as the xr residual buffer
    float* buf0 = (float*)d_ws;                   // [25088,384]: ln1-out -> attn-out -> ln2-out
    const size_t BUF0 = (size_t)TOKENS * CC;      // 9,633,792 floats
    float* region = buf0 + BUF0;                  // chunked qkv / fc1-hidden

    // adaptive chunk sizes (images per chunk) from the actual workspace budget
    const size_t availF = ws_size / sizeof(float);
    const size_t R = (availF > BUF0) ? (availF - BUF0) : 0;
    int gq = 2;                                   // images per qkv chunk (qkv: g*3136*1152 floats)
    if (R >= (size_t)8 * TPI * 3 * CC)      gq = 8;
    else if (R >= (size_t)4 * TPI * 3 * CC) gq = 4;
    int gh = 2;                                   // images per MLP chunk (hidden: g*3136*1536 floats)
    if (R >= (size_t)8 * TPI * HID)      gh = 8;
    else if (R >= (size_t)4 * TPI * HID) gh = 4;

    // 1. LN1 + cyclic shift + window partition -> buf0 (window-ordered)
    ln_kernel<true><<<TOKENS, 128, 0, stream>>>(x, n1g, n1b, buf0);

    // 2+3. per-chunk: QKV GEMM -> region, then windowed attention -> buf0 (rows of this chunk)
    for (int c = 0; c < 8 / gq; ++c) {
        const float* A = buf0 + (size_t)c * gq * TPI * CC;
        int M = gq * TPI;                          // multiple of 128 for gq in {2,4,8}
        dim3 g((3 * CC) / 128, M / 128);
        gemm128<EPI_BIAS><<<g, 256, 0, stream>>>(A, qkv_w, qkv_b, nullptr, region, M, 3 * CC, CC);
        attn_kernel<<<gq * NWIN * HEADS, 256, 0, stream>>>(region, amask, rpb, buf0, c * gq * NWIN);
    }

    // 4. proj GEMM + window reverse + roll + residual -> xr (= d_out)
    {
        dim3 g(CC / 128, TOKENS / 128);
        gemm128<EPI_PROJ><<<g, 256, 0, stream>>>(buf0, proj_w, proj_b, x, xr, TOKENS, CC, CC);
    }

    // 5. LN2 -> buf0
    ln_kernel<false><<<TOKENS, 128, 0, stream>>>(xr, n2g, n2b, buf0);

    // 6+7. per-chunk: fc1+GELU -> region, fc2 + residual -> d_out (in-place over xr rows, thread-local RAW)
    for (int c = 0; c < 8 / gh; ++c) {
        size_t off = (size_t)c * gh * TPI;
        int M = gh * TPI;
        {
            dim3 g(HID / 128, M / 128);
            gemm128<EPI_GELU><<<g, 256, 0, stream>>>(buf0 + off * CC, fc1w, fc1b, nullptr, region, M, HID, CC);
        }
        {
            dim3 g(CC / 128, M / 128);
            gemm128<EPI_FC2><<<g, 256, 0, stream>>>(region, fc2w, fc2b, xr + off * CC, (float*)d_out + off * CC, M, CC, HID);
        }
    }
}

// Round 3
// 539.729 us; speedup vs baseline: 2.4884x; 2.4884x over previous
//
#include <hip/hip_runtime.h>
#include <hip/hip_bf16.h>
#include <math.h>

#define BD 8
#define HH 56
#define WW 56
#define CC 384
#define HEADS 12
#define HD 32
#define WS 7
#define SS 3
#define NTOK 49
#define NWIN 64            // windows per image (8x8)
#define TOKENS (BD*HH*WW)  // 25088
#define HID 1536
#define TPI (HH*WW)        // tokens per image: 3136

typedef __attribute__((ext_vector_type(8))) short bf16x8;
typedef __attribute__((ext_vector_type(4))) float f32x4;
typedef unsigned short ushort_t;

__device__ __forceinline__ unsigned short f2bf(float f) {
    unsigned int u = __float_as_uint(f);
    unsigned int r = (u + 0x7FFFu + ((u >> 16) & 1u)) >> 16;
    return (unsigned short)r;
}
__device__ __forceinline__ float bf2f(unsigned short h) {
    return __uint_as_float(((unsigned int)h) << 16);
}
__device__ __forceinline__ void gload16(const void* g, void* l) {
    __builtin_amdgcn_global_load_lds((const __attribute__((address_space(1))) unsigned int*)g,
                                     (__attribute__((address_space(3))) unsigned int*)l, 16, 0, 0);
}

// ---------------- Weight prep: W[K][N] fp32 -> Wt_hi[N][K], Wt_lo[N][K] bf16 (transpose+split) ----
__global__ __launch_bounds__(256)
void wprep(const float* __restrict__ W, unsigned short* __restrict__ Th,
           unsigned short* __restrict__ Tl, int K, int N)
{
    __shared__ float t[32][33];
    int n0 = blockIdx.x * 32, k0 = blockIdx.y * 32;
    int c = threadIdx.x & 31, r = threadIdx.x >> 5;   // r: 0..7
    #pragma unroll
    for (int rr = 0; rr < 32; rr += 8)
        t[r + rr][c] = W[(size_t)(k0 + r + rr) * N + n0 + c];
    __syncthreads();
    #pragma unroll
    for (int rr = 0; rr < 32; rr += 8) {
        int i = r + rr;                 // n-local
        float v = t[c][i];              // = W[k0+c][n0+i]
        unsigned short h = f2bf(v);
        Th[(size_t)(n0 + i) * K + k0 + c] = h;
        Tl[(size_t)(n0 + i) * K + k0 + c] = f2bf(v - bf2f(h));
    }
}

// ---------------- LayerNorm -> hi/lo bf16 (optionally fused shift+window gather) ----------------
template<bool SHIFT>
__global__ __launch_bounds__(128)
void ln_kernel(const float* __restrict__ in, const float* __restrict__ g,
               const float* __restrict__ beta, unsigned short* __restrict__ oh,
               unsigned short* __restrict__ ol)
{
    int m = blockIdx.x;
    const float* src;
    size_t dbase = (size_t)m * CC;
    if (SHIFT) {
        int b  = m / (NWIN * NTOK);
        int rr = m % (NWIN * NTOK);
        int w  = rr / NTOK;
        int t  = rr % NTOK;
        int wh = w >> 3, ww = w & 7;
        int ti = t / 7,  tj = t - (t / 7) * 7;
        int hh = wh * WS + ti + SS;  if (hh >= HH) hh -= HH;
        int w2 = ww * WS + tj + SS;  if (w2 >= WW) w2 -= WW;
        src = in + ((size_t)b * TPI + hh * WW + w2) * CC;
    } else {
        src = in + (size_t)m * CC;
    }
    int tid = threadIdx.x;
    float v0 = src[tid], v1 = src[tid + 128], v2 = src[tid + 256];
    float s  = v0 + v1 + v2;
    float ss = v0*v0 + v1*v1 + v2*v2;
    #pragma unroll
    for (int off = 32; off > 0; off >>= 1) {
        s  += __shfl_down(s, off);
        ss += __shfl_down(ss, off);
    }
    __shared__ float red[4];
    int wid = tid >> 6, lane = tid & 63;
    if (lane == 0) { red[wid] = s; red[wid + 2] = ss; }
    __syncthreads();
    float tot   = red[0] + red[1];
    float totss = red[2] + red[3];
    float mu   = tot * (1.0f / CC);
    float var  = totss * (1.0f / CC) - mu * mu;
    float rstd = rsqrtf(var + 1e-5f);
    #pragma unroll
    for (int e = 0; e < 3; ++e) {
        int idx = tid + e * 128;
        float v = (e == 0 ? v0 : (e == 1 ? v1 : v2));
        float y = (v - mu) * rstd * g[idx] + beta[idx];
        unsigned short h = f2bf(y);
        oh[dbase + idx] = h;
        ol[dbase + idx] = f2bf(y - bf2f(h));
    }
}

// ---------------- split-bf16 MFMA GEMM: 128x128 tile, BK=32, 4 waves ----------------
// C = Ah*Bh + Ah*Bl (+ Al*Bh if ASPLIT).  A:[M][K] bf16 hi/lo, B:[N][K] bf16 hi/lo (pre-transposed)
#define EPI_BIAS 0   // outf = acc + bias                       (qkv, fp32)
#define EPI_GELU 1   // outh = bf16(gelu(acc + bias))           (fc1)
#define EPI_PROJ 2   // outf[pix] = extra[pix] + acc + bias     (proj + window-reverse + roll + residual)
#define EPI_FC2  3   // outf = extra + acc + bias               (fc2 + residual)

template<int EPI, bool ASPLIT>
__global__ __launch_bounds__(256)
void gemm_mfma(const unsigned short* __restrict__ Ahi, const unsigned short* __restrict__ Alo,
               const unsigned short* __restrict__ Bhi, const unsigned short* __restrict__ Blo,
               const float* __restrict__ bias, const float* __restrict__ extra,
               float* __restrict__ outf, unsigned short* __restrict__ outh,
               int M, int N, int K)
{
    constexpr int NBUF = ASPLIT ? 4 : 3;
    constexpr int PER  = ASPLIT ? 8 : 6;      // staging segments per wave
    __shared__ unsigned short lds[NBUF][128][32];

    int tid  = threadIdx.x;
    int lane = tid & 63;
    int wave = tid >> 6;
    int wr = wave >> 1, wc = wave & 1;
    int m0 = blockIdx.y * 128, n0 = blockIdx.x * 128;

    int lrow = lane >> 2;      // staging row within 16-row chunk
    int ps   = lane & 3;       // staging 16B slot
    int kslot = lane >> 4;     // frag k-chunk
    int rA    = lane & 15;     // frag row/col

    f32x4 acc[4][4];
    #pragma unroll
    for (int i = 0; i < 4; ++i)
        #pragma unroll
        for (int j = 0; j < 4; ++j)
            acc[i][j] = (f32x4){0.f, 0.f, 0.f, 0.f};

    for (int k0 = 0; k0 < K; k0 += 32) {
        #pragma unroll
        for (int s = 0; s < PER; ++s) {
            int seg = wave * PER + s;
            int bf = seg >> 3, c = seg & 7;
            const unsigned short* gb; int r0;
            if (ASPLIT) {
                if      (bf == 0) { gb = Ahi; r0 = m0; }
                else if (bf == 1) { gb = Alo; r0 = m0; }
                else if (bf == 2) { gb = Bhi; r0 = n0; }
                else              { gb = Blo; r0 = n0; }
            } else {
                if      (bf == 0) { gb = Ahi; r0 = m0; }
                else if (bf == 1) { gb = Bhi; r0 = n0; }
                else              { gb = Blo; r0 = n0; }
            }
            int row = c * 16 + lrow;
            int ks = ps ^ ((row >> 1) & 3);
            gload16(gb + (size_t)(r0 + row) * K + k0 + ks * 8, &lds[bf][c * 16][0]);
        }
        __syncthreads();

        bf16x8 ah[4], al[4], bh[4], bl[4];
        #pragma unroll
        for (int f = 0; f < 4; ++f) {
            int row = wr * 64 + f * 16 + rA;
            int p = (kslot ^ ((row >> 1) & 3)) * 8;
            ah[f] = *(const bf16x8*)&lds[0][row][p];
            if (ASPLIT) al[f] = *(const bf16x8*)&lds[1][row][p];
            int col = wc * 64 + f * 16 + rA;
            int pb = (kslot ^ ((col >> 1) & 3)) * 8;
            bh[f] = *(const bf16x8*)&lds[ASPLIT ? 2 : 1][col][pb];
            bl[f] = *(const bf16x8*)&lds[ASPLIT ? 3 : 2][col][pb];
        }
        #pragma unroll
        for (int i = 0; i < 4; ++i)
            #pragma unroll
            for (int j = 0; j < 4; ++j)
                acc[i][j] = __builtin_amdgcn_mfma_f32_16x16x32_bf16(ah[i], bh[j], acc[i][j], 0, 0, 0);
        #pragma unroll
        for (int i = 0; i < 4; ++i)
            #pragma unroll
            for (int j = 0; j < 4; ++j)
                acc[i][j] = __builtin_amdgcn_mfma_f32_16x16x32_bf16(ah[i], bl[j], acc[i][j], 0, 0, 0);
        if (ASPLIT) {
            #pragma unroll
            for (int i = 0; i < 4; ++i)
                #pragma unroll
                for (int j = 0; j < 4; ++j)
                    acc[i][j] = __builtin_amdgcn_mfma_f32_16x16x32_bf16(al[i], bh[j], acc[i][j], 0, 0, 0);
        }
        __syncthreads();
    }

    // epilogue: D row = (lane>>4)*4 + reg, col = lane&15  (per frag)
    int cn = lane & 15;
    int rb = (lane >> 4) * 4;
    float bj[4];
    #pragma unroll
    for (int j = 0; j < 4; ++j) bj[j] = bias[n0 + wc * 64 + j * 16 + cn];
    int ncol = n0 + wc * 64 + cn;

    #pragma unroll
    for (int i = 0; i < 4; ++i) {
        #pragma unroll
        for (int r = 0; r < 4; ++r) {
            int mg = m0 + wr * 64 + i * 16 + rb + r;
            if (EPI == EPI_BIAS) {
                float* orow = outf + (size_t)mg * N + ncol;
                #pragma unroll
                for (int j = 0; j < 4; ++j) orow[j * 16] = acc[i][j][r] + bj[j];
            } else if (EPI == EPI_GELU) {
                unsigned short* orow = outh + (size_t)mg * N + ncol;
                #pragma unroll
                for (int j = 0; j < 4; ++j) {
                    float t = acc[i][j][r] + bj[j];
                    float gl = 0.5f * t * (1.0f + erff(t * 0.70710678118654752f));
                    orow[j * 16] = f2bf(gl);
                }
            } else if (EPI == EPI_PROJ) {
                int b  = mg / (NWIN * NTOK);
                int rr = mg % (NWIN * NTOK);
                int w  = rr / NTOK;
                int t  = rr % NTOK;
                int wh = w >> 3, ww = w & 7;
                int ti = t / 7,  tj = t - (t / 7) * 7;
                int hh = wh * WS + ti + SS;  if (hh >= HH) hh -= HH;
                int w2 = ww * WS + tj + SS;  if (w2 >= WW) w2 -= WW;
                size_t pix = (size_t)b * TPI + hh * WW + w2;
                const float* xin = extra + pix * CC + ncol;
                float* xo = outf + pix * CC + ncol;
                #pragma unroll
                for (int j = 0; j < 4; ++j) xo[j * 16] = xin[j * 16] + acc[i][j][r] + bj[j];
            } else { // EPI_FC2
                const float* xi = extra + (size_t)mg * N + ncol;
                float* xo = outf + (size_t)mg * N + ncol;
                #pragma unroll
                for (int j = 0; j < 4; ++j) xo[j * 16] = xi[j * 16] + acc[i][j][r] + bj[j];
            }
        }
    }
}

// ---------------- Windowed attention (fp32 in, hi/lo bf16 out) ----------------
__global__ __launch_bounds__(256)
void attn_kernel(const float* __restrict__ qkv, const float* __restrict__ amask,
                 const float* __restrict__ rpb, unsigned short* __restrict__ oh,
                 unsigned short* __restrict__ ol, int win0)
{
    int bid  = blockIdx.x;
    int head = bid % HEADS;
    int winl = bid / HEADS;
    int wing = win0 + winl;
    int wl   = wing & (NWIN - 1);
    int qbase = winl * NTOK;
    int obase = wing * NTOK;

    __shared__ float Q[NTOK][HD + 1];
    __shared__ float Kk[NTOK][HD + 1];
    __shared__ float V[NTOK][HD + 1];
    __shared__ float S[NTOK][52];

    int tid = threadIdx.x;
    const float scale = 0.17677669529663687f;

    for (int idx = tid; idx < NTOK * HD; idx += 256) {
        int t = idx >> 5, d = idx & 31;
        size_t row = (size_t)(qbase + t) * (3 * CC) + head * HD + d;
        Q[t][d]  = qkv[row] * scale;
        Kk[t][d] = qkv[row + CC];
        V[t][d]  = qkv[row + 2 * CC];
    }
    __syncthreads();

    for (int idx = tid; idx < NTOK * NTOK; idx += 256) {
        int i = idx / NTOK, j = idx % NTOK;
        float acc = 0.0f;
        #pragma unroll
        for (int d = 0; d < HD; d++) acc += Q[i][d] * Kk[j][d];
        int yi = i / 7, xi = i - yi * 7;
        int yj = j / 7, xj = j - yj * 7;
        int rel = (yi - yj + WS - 1) * (2 * WS - 1) + (xi - xj + WS - 1);
        acc += rpb[rel * HEADS + head];
        acc += amask[((size_t)wl * NTOK + i) * NTOK + j];
        S[i][j] = acc;
    }
    __syncthreads();

    if (tid < NTOK) {
        float mx = -1e30f;
        #pragma unroll 7
        for (int j = 0; j < NTOK; j++) mx = fmaxf(mx, S[tid][j]);
        float sum = 0.0f;
        #pragma unroll 7
        for (int j = 0; j < NTOK; j++) { float e = __expf(S[tid][j] - mx); S[tid][j] = e; sum += e; }
        float inv = 1.0f / sum;
        #pragma unroll 7
        for (int j = 0; j < NTOK; j++) S[tid][j] *= inv;
    }
    __syncthreads();

    for (int idx = tid; idx < NTOK * HD; idx += 256) {
        int t = idx >> 5, d = idx & 31;
        float acc = 0.0f;
        #pragma unroll
        for (int j = 0; j < NTOK; j++) acc += S[t][j] * V[j][d];
        size_t o = (size_t)(obase + t) * CC + head * HD + d;
        unsigned short h = f2bf(acc);
        oh[o] = h;
        ol[o] = f2bf(acc - bf2f(h));
    }
}

// ---------------- launcher ----------------
extern "C" void kernel_launch(void* const* d_in, const int* in_sizes, int n_in,
                              void* d_out, int out_size, void* d_ws, size_t ws_size,
                              hipStream_t stream)
{
    const float* x      = (const float*)d_in[0];
    const float* amask  = (const float*)d_in[1];
    const float* qkv_w  = (const float*)d_in[2];
    const float* qkv_b  = (const float*)d_in[3];
    const float* proj_w = (const float*)d_in[4];
    const float* proj_b = (const float*)d_in[5];
    const float* rpb    = (const float*)d_in[6];
    const float* n1g    = (const float*)d_in[7];
    const float* n1b    = (const float*)d_in[8];
    const float* n2g    = (const float*)d_in[9];
    const float* n2b    = (const float*)d_in[10];
    const float* fc1w   = (const float*)d_in[11];
    const float* fc1b   = (const float*)d_in[12];
    const float* fc2w   = (const float*)d_in[13];
    const float* fc2b   = (const float*)d_in[14];

    float* xr = (float*)d_out;                     // d_out doubles as xr residual buffer

    // ---- workspace carve-up (ushort granularity) ----
    unsigned short* p = (unsigned short*)d_ws;
    unsigned short* Wqh = p; p += 442368;  unsigned short* Wql = p; p += 442368;
    unsigned short* Wph = p; p += 147456;  unsigned short* Wpl = p; p += 147456;
    unsigned short* W1h = p; p += 589824;  unsigned short* W1l = p; p += 589824;
    unsigned short* W2h = p; p += 589824;  unsigned short* W2l = p; p += 589824;
    unsigned short* ABh = p; p += (size_t)TOKENS * CC;
    unsigned short* ABl = p; p += (size_t)TOKENS * CC;
    float* region = (float*)p;                     // 45,613,056 bytes used so far
    unsigned short* Hbuf = (unsigned short*)p;

    const size_t FIXED = 45613056;
    size_t R = (ws_size > FIXED) ? ws_size - FIXED : 0;
    int gq = 2;                                    // images per qkv chunk (fp32: g*3136*1152*4 B)
    if (R >= (size_t)8 * TPI * 3 * CC * 4)      gq = 8;
    else if (R >= (size_t)4 * TPI * 3 * CC * 4) gq = 4;
    int gh = 2;                                    // images per MLP chunk (bf16: g*3136*1536*2 B)
    if (R >= (size_t)8 * TPI * HID * 2)      gh = 8;
    else if (R >= (size_t)4 * TPI * HID * 2) gh = 4;

    // 0. weight transpose + hi/lo split
    wprep<<<dim3(1152/32, 384/32), 256, 0, stream>>>(qkv_w, Wqh, Wql, 384, 1152);
    wprep<<<dim3(384/32,  384/32), 256, 0, stream>>>(proj_w, Wph, Wpl, 384, 384);
    wprep<<<dim3(1536/32, 384/32), 256, 0, stream>>>(fc1w,  W1h, W1l, 384, 1536);
    wprep<<<dim3(384/32, 1536/32), 256, 0, stream>>>(fc2w,  W2h, W2l, 1536, 384);

    // 1. LN1 + shift + window partition -> AB hi/lo (window-ordered)
    ln_kernel<true><<<TOKENS, 128, 0, stream>>>(x, n1g, n1b, ABh, ABl);

    // 2+3. per-chunk: QKV GEMM (fp32 out) -> region, attention -> AB hi/lo (same rows, sequential)
    for (int c = 0; c < 8 / gq; ++c) {
        size_t off = (size_t)c * gq * TPI;
        int M = gq * TPI;
        dim3 g((3 * CC) / 128, M / 128);
        gemm_mfma<EPI_BIAS, true><<<g, 256, 0, stream>>>(
            ABh + off * CC, ABl + off * CC, Wqh, Wql, qkv_b, nullptr, region, nullptr, M, 3 * CC, CC);
        attn_kernel<<<gq * NWIN * HEADS, 256, 0, stream>>>(region, amask, rpb, ABh, ABl, c * gq * NWIN);
    }

    // 4. proj GEMM + window reverse + roll + residual -> xr (= d_out)
    {
        dim3 g(CC / 128, TOKENS / 128);
        gemm_mfma<EPI_PROJ, true><<<g, 256, 0, stream>>>(
            ABh, ABl, Wph, Wpl, proj_b, x, xr, nullptr, TOKENS, CC, CC);
    }

    // 5. LN2 -> AB hi/lo
    ln_kernel<false><<<TOKENS, 128, 0, stream>>>(xr, n2g, n2b, ABh, ABl);

    // 6+7. per-chunk: fc1+GELU -> Hbuf (single bf16), fc2 + residual -> d_out
    for (int c = 0; c < 8 / gh; ++c) {
        size_t off = (size_t)c * gh * TPI;
        int M = gh * TPI;
        {
            dim3 g(HID / 128, M / 128);
            gemm_mfma<EPI_GELU, true><<<g, 256, 0, stream>>>(
                ABh + off * CC, ABl + off * CC, W1h, W1l, fc1b, nullptr, nullptr, Hbuf, M, HID, CC);
        }
        {
            dim3 g(CC / 128, M / 128);
            gemm_mfma<EPI_FC2, false><<<g, 256, 0, stream>>>(
                Hbuf, nullptr, W2h, W2l, fc2b, xr + off * CC, (float*)d_out + off * CC, nullptr, M, CC, HID);
        }
    }
}

// Round 4
// 532.904 us; speedup vs baseline: 2.5203x; 1.0128x over previous
//
#include <hip/hip_runtime.h>
#include <hip/hip_bf16.h>
#include <math.h>

#define BD 8
#define HH 56
#define WW 56
#define CC 384
#define HEADS 12
#define HD 32
#define WS 7
#define SS 3
#define NTOK 49
#define NWIN 64            // windows per image (8x8)
#define TOKENS (BD*HH*WW)  // 25088
#define HID 1536
#define TPI (HH*WW)        // tokens per image: 3136

typedef __attribute__((ext_vector_type(8))) short bf16x8;
typedef __attribute__((ext_vector_type(4))) float f32x4;

__device__ __forceinline__ unsigned short f2bf(float f) {
    unsigned int u = __float_as_uint(f);
    unsigned int r = (u + 0x7FFFu + ((u >> 16) & 1u)) >> 16;
    return (unsigned short)r;
}
__device__ __forceinline__ float bf2f(unsigned short h) {
    return __uint_as_float(((unsigned int)h) << 16);
}
__device__ __forceinline__ void gload16(const void* g, void* l) {
    __builtin_amdgcn_global_load_lds((const __attribute__((address_space(1))) unsigned int*)g,
                                     (__attribute__((address_space(3))) unsigned int*)l, 16, 0, 0);
}

// ---------------- Weight prep: W[K][N] fp32 -> Wt_hi[N][K], Wt_lo[N][K] bf16 (transpose+split) ----
__global__ __launch_bounds__(256)
void wprep(const float* __restrict__ W, unsigned short* __restrict__ Th,
           unsigned short* __restrict__ Tl, int K, int N)
{
    __shared__ float t[32][33];
    int n0 = blockIdx.x * 32, k0 = blockIdx.y * 32;
    int c = threadIdx.x & 31, r = threadIdx.x >> 5;   // r: 0..7
    #pragma unroll
    for (int rr = 0; rr < 32; rr += 8)
        t[r + rr][c] = W[(size_t)(k0 + r + rr) * N + n0 + c];
    __syncthreads();
    #pragma unroll
    for (int rr = 0; rr < 32; rr += 8) {
        int i = r + rr;                 // n-local
        float v = t[c][i];              // = W[k0+c][n0+i]
        unsigned short h = f2bf(v);
        Th[(size_t)(n0 + i) * K + k0 + c] = h;
        Tl[(size_t)(n0 + i) * K + k0 + c] = f2bf(v - bf2f(h));
    }
}

// ---------------- LayerNorm -> bf16 (optionally fused shift+window gather) ----------------
template<bool SHIFT>
__global__ __launch_bounds__(128)
void ln_kernel(const float* __restrict__ in, const float* __restrict__ g,
               const float* __restrict__ beta, unsigned short* __restrict__ oh)
{
    int m = blockIdx.x;
    const float* src;
    size_t dbase = (size_t)m * CC;
    if (SHIFT) {
        int b  = m / (NWIN * NTOK);
        int rr = m % (NWIN * NTOK);
        int w  = rr / NTOK;
        int t  = rr % NTOK;
        int wh = w >> 3, ww = w & 7;
        int ti = t / 7,  tj = t - (t / 7) * 7;
        int hh = wh * WS + ti + SS;  if (hh >= HH) hh -= HH;
        int w2 = ww * WS + tj + SS;  if (w2 >= WW) w2 -= WW;
        src = in + ((size_t)b * TPI + hh * WW + w2) * CC;
    } else {
        src = in + (size_t)m * CC;
    }
    int tid = threadIdx.x;
    float v0 = src[tid], v1 = src[tid + 128], v2 = src[tid + 256];
    float s  = v0 + v1 + v2;
    float ss = v0*v0 + v1*v1 + v2*v2;
    #pragma unroll
    for (int off = 32; off > 0; off >>= 1) {
        s  += __shfl_down(s, off);
        ss += __shfl_down(ss, off);
    }
    __shared__ float red[4];
    int wid = tid >> 6, lane = tid & 63;
    if (lane == 0) { red[wid] = s; red[wid + 2] = ss; }
    __syncthreads();
    float tot   = red[0] + red[1];
    float totss = red[2] + red[3];
    float mu   = tot * (1.0f / CC);
    float var  = totss * (1.0f / CC) - mu * mu;
    float rstd = rsqrtf(var + 1e-5f);
    #pragma unroll
    for (int e = 0; e < 3; ++e) {
        int idx = tid + e * 128;
        float v = (e == 0 ? v0 : (e == 1 ? v1 : v2));
        float y = (v - mu) * rstd * g[idx] + beta[idx];
        oh[dbase + idx] = f2bf(y);
    }
}

// ---------------- 2-pass split-bf16 MFMA GEMM: 128x128 tile, BK=32, 4 waves ----------------
// C = Ah*Bh + Ah*Bl.  A:[M][K] bf16, B:[N][K] bf16 hi/lo (pre-transposed)
#define EPI_QKV  0   // outh = bf16(acc + bias)                 (qkv)
#define EPI_GELU 1   // outh = bf16(gelu(acc + bias))           (fc1)
#define EPI_PROJ 2   // outf[pix] = extra[pix] + acc + bias     (proj + window-reverse + roll + residual)
#define EPI_FC2  3   // outf = extra + acc + bias               (fc2 + residual)

template<int EPI>
__global__ __launch_bounds__(256)
void gemm_mfma(const unsigned short* __restrict__ Ah,
               const unsigned short* __restrict__ Bh, const unsigned short* __restrict__ Bl,
               const float* __restrict__ bias, const float* __restrict__ extra,
               float* __restrict__ outf, unsigned short* __restrict__ outh,
               int M, int N, int K)
{
    __shared__ unsigned short lds[3][128][32];

    int tid  = threadIdx.x;
    int lane = tid & 63;
    int wave = tid >> 6;
    int wr = wave >> 1, wc = wave & 1;
    int m0 = blockIdx.y * 128, n0 = blockIdx.x * 128;

    int lrow = lane >> 2;      // staging row within 16-row chunk
    int ps   = lane & 3;       // staging 16B slot
    int kslot = lane >> 4;     // frag k-chunk
    int rA    = lane & 15;     // frag row/col

    f32x4 acc[4][4];
    #pragma unroll
    for (int i = 0; i < 4; ++i)
        #pragma unroll
        for (int j = 0; j < 4; ++j)
            acc[i][j] = (f32x4){0.f, 0.f, 0.f, 0.f};

    for (int k0 = 0; k0 < K; k0 += 32) {
        #pragma unroll
        for (int s = 0; s < 6; ++s) {
            int seg = wave * 6 + s;          // 0..23
            int bf = seg >> 3, c = seg & 7;
            const unsigned short* gb = (bf == 0) ? Ah : (bf == 1) ? Bh : Bl;
            int r0 = (bf == 0) ? m0 : n0;
            int row = c * 16 + lrow;
            int ks = ps ^ ((row >> 1) & 3);
            gload16(gb + (size_t)(r0 + row) * K + k0 + ks * 8, &lds[bf][c * 16][0]);
        }
        __syncthreads();

        bf16x8 ah[4], bh[4], bl[4];
        #pragma unroll
        for (int f = 0; f < 4; ++f) {
            int row = wr * 64 + f * 16 + rA;
            int p = (kslot ^ ((row >> 1) & 3)) * 8;
            ah[f] = *(const bf16x8*)&lds[0][row][p];
            int col = wc * 64 + f * 16 + rA;
            int pb = (kslot ^ ((col >> 1) & 3)) * 8;
            bh[f] = *(const bf16x8*)&lds[1][col][pb];
            bl[f] = *(const bf16x8*)&lds[2][col][pb];
        }
        #pragma unroll
        for (int i = 0; i < 4; ++i)
            #pragma unroll
            for (int j = 0; j < 4; ++j)
                acc[i][j] = __builtin_amdgcn_mfma_f32_16x16x32_bf16(ah[i], bh[j], acc[i][j], 0, 0, 0);
        #pragma unroll
        for (int i = 0; i < 4; ++i)
            #pragma unroll
            for (int j = 0; j < 4; ++j)
                acc[i][j] = __builtin_amdgcn_mfma_f32_16x16x32_bf16(ah[i], bl[j], acc[i][j], 0, 0, 0);
        __syncthreads();
    }

    // epilogue: D row = (lane>>4)*4 + reg, col = lane&15  (per frag)
    int cn = lane & 15;
    int rb = (lane >> 4) * 4;
    float bj[4];
    #pragma unroll
    for (int j = 0; j < 4; ++j) bj[j] = bias[n0 + wc * 64 + j * 16 + cn];
    int ncol = n0 + wc * 64 + cn;

    #pragma unroll
    for (int i = 0; i < 4; ++i) {
        #pragma unroll
        for (int r = 0; r < 4; ++r) {
            int mg = m0 + wr * 64 + i * 16 + rb + r;
            if (EPI == EPI_QKV) {
                unsigned short* orow = outh + (size_t)mg * N + ncol;
                #pragma unroll
                for (int j = 0; j < 4; ++j) orow[j * 16] = f2bf(acc[i][j][r] + bj[j]);
            } else if (EPI == EPI_GELU) {
                unsigned short* orow = outh + (size_t)mg * N + ncol;
                #pragma unroll
                for (int j = 0; j < 4; ++j) {
                    float t = acc[i][j][r] + bj[j];
                    float gl = 0.5f * t * (1.0f + erff(t * 0.70710678118654752f));
                    orow[j * 16] = f2bf(gl);
                }
            } else if (EPI == EPI_PROJ) {
                int b  = mg / (NWIN * NTOK);
                int rr = mg % (NWIN * NTOK);
                int w  = rr / NTOK;
                int t  = rr % NTOK;
                int wh = w >> 3, ww = w & 7;
                int ti = t / 7,  tj = t - (t / 7) * 7;
                int hh = wh * WS + ti + SS;  if (hh >= HH) hh -= HH;
                int w2 = ww * WS + tj + SS;  if (w2 >= WW) w2 -= WW;
                size_t pix = (size_t)b * TPI + hh * WW + w2;
                const float* xin = extra + pix * CC + ncol;
                float* xo = outf + pix * CC + ncol;
                #pragma unroll
                for (int j = 0; j < 4; ++j) xo[j * 16] = xin[j * 16] + acc[i][j][r] + bj[j];
            } else { // EPI_FC2
                const float* xi = extra + (size_t)mg * N + ncol;
                float* xo = outf + (size_t)mg * N + ncol;
                #pragma unroll
                for (int j = 0; j < 4; ++j) xo[j * 16] = xi[j * 16] + acc[i][j][r] + bj[j];
            }
        }
    }
}

// ---------------- Attention v2: one wave per (window, head), lane-local softmax ----------------
// qkvb: chunk-local bf16 [g*NWIN*NTOK][1152]; outh: global bf16 AB buffer
__global__ __launch_bounds__(64)
void attn2(const unsigned short* __restrict__ qkvb, const float* __restrict__ rpb,
           unsigned short* __restrict__ outh, int win0)
{
    int unit = blockIdx.x;
    int head = unit % HEADS;
    int winl = unit / HEADS;
    int wing = win0 + winl;
    int wl   = wing & (NWIN - 1);
    int wh = wl >> 3, ww = wl & 7;
    int qbase = winl * NTOK;
    int obase = wing * NTOK;

    __shared__ float Ksh[NTOK * 32];
    __shared__ float Vsh[NTOK * 32];
    __shared__ float RP[169];

    int lane = threadIdx.x;

    // stage K,V (bf16 -> fp32), 8 elems per iteration per lane
    for (int idx = lane; idx < NTOK * 4; idx += 64) {
        int t = idx >> 2, seg = idx & 3;
        size_t rowb = (size_t)(qbase + t) * 1152 + head * HD + seg * 8;
        uint4 u = *(const uint4*)(qkvb + rowb + CC);
        float* kd = &Ksh[t * 32 + seg * 8];
        kd[0] = __uint_as_float((u.x & 0xffffu) << 16); kd[1] = __uint_as_float(u.x & 0xffff0000u);
        kd[2] = __uint_as_float((u.y & 0xffffu) << 16); kd[3] = __uint_as_float(u.y & 0xffff0000u);
        kd[4] = __uint_as_float((u.z & 0xffffu) << 16); kd[5] = __uint_as_float(u.z & 0xffff0000u);
        kd[6] = __uint_as_float((u.w & 0xffffu) << 16); kd[7] = __uint_as_float(u.w & 0xffff0000u);
        uint4 v = *(const uint4*)(qkvb + rowb + 2 * CC);
        float* vd = &Vsh[t * 32 + seg * 8];
        vd[0] = __uint_as_float((v.x & 0xffffu) << 16); vd[1] = __uint_as_float(v.x & 0xffff0000u);
        vd[2] = __uint_as_float((v.y & 0xffffu) << 16); vd[3] = __uint_as_float(v.y & 0xffff0000u);
        vd[4] = __uint_as_float((v.z & 0xffffu) << 16); vd[5] = __uint_as_float(v.z & 0xffff0000u);
        vd[6] = __uint_as_float((v.w & 0xffffu) << 16); vd[7] = __uint_as_float(v.w & 0xffff0000u);
    }
    for (int idx = lane; idx < 169; idx += 64) RP[idx] = rpb[idx * HEADS + head];
    __syncthreads();

    int r = (lane < NTOK) ? lane : (NTOK - 1);
    int ti = r / 7, tj = r - ti * 7;
    int lh_i = (wh == 7) ? (ti < 4 ? 1 : 2) : 0;
    int lw_i = (ww == 7) ? (tj < 4 ? 1 : 2) : 0;

    // Q row -> registers (scaled)
    const float scale = 0.17677669529663687f;   // 1/sqrt(32)
    float q[32];
    {
        const uint4* q4p = (const uint4*)(qkvb + (size_t)(qbase + r) * 1152 + head * HD);
        #pragma unroll
        for (int v = 0; v < 4; ++v) {
            uint4 u = q4p[v];
            unsigned int wv[4] = {u.x, u.y, u.z, u.w};
            #pragma unroll
            for (int e = 0; e < 4; ++e) {
                q[v * 8 + e * 2]     = __uint_as_float((wv[e] & 0xffffu) << 16) * scale;
                q[v * 8 + e * 2 + 1] = __uint_as_float(wv[e] & 0xffff0000u) * scale;
            }
        }
    }

    // scores: QK^T + rel-pos bias + analytic shift mask (lane-local row)
    float s[NTOK];
    #pragma unroll
    for (int j = 0; j < NTOK; ++j) {
        const float* kr = &Ksh[j * 32];
        float acc = 0.0f;
        #pragma unroll
        for (int d = 0; d < 32; ++d) acc = fmaf(q[d], kr[d], acc);
        int yj = j / 7, xj = j - yj * 7;
        int rel = (ti - yj + 6) * 13 + (tj - xj + 6);
        acc += RP[rel];
        int lh_j = (wh == 7) ? (yj < 4 ? 1 : 2) : 0;
        int lw_j = (ww == 7) ? (xj < 4 ? 1 : 2) : 0;
        if (lh_i != lh_j || lw_i != lw_j) acc -= 100.0f;
        s[j] = acc;
    }

    // lane-local softmax
    float mx = -1e30f;
    #pragma unroll
    for (int j = 0; j < NTOK; ++j) mx = fmaxf(mx, s[j]);
    float sum = 0.0f;
    #pragma unroll
    for (int j = 0; j < NTOK; ++j) { s[j] = __expf(s[j] - mx); sum += s[j]; }
    float inv = 1.0f / sum;

    // PV
    float o[32];
    #pragma unroll
    for (int d = 0; d < 32; ++d) o[d] = 0.0f;
    #pragma unroll
    for (int j = 0; j < NTOK; ++j) {
        float p = s[j];
        const float* vr = &Vsh[j * 32];
        #pragma unroll
        for (int d = 0; d < 32; ++d) o[d] = fmaf(p, vr[d], o[d]);
    }

    if (lane < NTOK) {
        unsigned short* orow = outh + (size_t)(obase + r) * CC + head * HD;
        #pragma unroll
        for (int v = 0; v < 4; ++v) {
            uint4 u;
            unsigned int wd[4];
            #pragma unroll
            for (int e = 0; e < 4; ++e) {
                unsigned int lo = f2bf(o[v * 8 + e * 2] * inv);
                unsigned int hi = f2bf(o[v * 8 + e * 2 + 1] * inv);
                wd[e] = lo | (hi << 16);
            }
            u.x = wd[0]; u.y = wd[1]; u.z = wd[2]; u.w = wd[3];
            *(uint4*)(orow + v * 8) = u;
        }
    }
}

// ---------------- launcher ----------------
extern "C" void kernel_launch(void* const* d_in, const int* in_sizes, int n_in,
                              void* d_out, int out_size, void* d_ws, size_t ws_size,
                              hipStream_t stream)
{
    const float* x      = (const float*)d_in[0];
    const float* qkv_w  = (const float*)d_in[2];
    const float* qkv_b  = (const float*)d_in[3];
    const float* proj_w = (const float*)d_in[4];
    const float* proj_b = (const float*)d_in[5];
    const float* rpb    = (const float*)d_in[6];
    const float* n1g    = (const float*)d_in[7];
    const float* n1b    = (const float*)d_in[8];
    const float* n2g    = (const float*)d_in[9];
    const float* n2b    = (const float*)d_in[10];
    const float* fc1w   = (const float*)d_in[11];
    const float* fc1b   = (const float*)d_in[12];
    const float* fc2w   = (const float*)d_in[13];
    const float* fc2b   = (const float*)d_in[14];

    float* xr = (float*)d_out;                     // d_out doubles as xr residual buffer

    // ---- workspace carve-up ----
    unsigned short* p = (unsigned short*)d_ws;
    unsigned short* Wqh = p; p += 442368;  unsigned short* Wql = p; p += 442368;
    unsigned short* Wph = p; p += 147456;  unsigned short* Wpl = p; p += 147456;
    unsigned short* W1h = p; p += 589824;  unsigned short* W1l = p; p += 589824;
    unsigned short* W2h = p; p += 589824;  unsigned short* W2l = p; p += 589824;
    unsigned short* ABh = p; p += (size_t)TOKENS * CC;
    unsigned short* region = p;                    // FIXED = 26,345,472 bytes before region
    unsigned short* Hbuf = region;

    const size_t FIXED = 26345472;
    size_t R = (ws_size > FIXED) ? ws_size - FIXED : 0;
    int gq = 2;                                    // images per qkv chunk (bf16: g*3136*1152*2 B)
    if (R >= (size_t)8 * TPI * 3 * CC * 2)      gq = 8;
    else if (R >= (size_t)4 * TPI * 3 * CC * 2) gq = 4;
    int gh = 2;                                    // images per MLP chunk (bf16: g*3136*1536*2 B)
    if (R >= (size_t)8 * TPI * HID * 2)      gh = 8;
    else if (R >= (size_t)4 * TPI * HID * 2) gh = 4;

    // 0. weight transpose + hi/lo split
    wprep<<<dim3(1152/32, 384/32), 256, 0, stream>>>(qkv_w, Wqh, Wql, 384, 1152);
    wprep<<<dim3(384/32,  384/32), 256, 0, stream>>>(proj_w, Wph, Wpl, 384, 384);
    wprep<<<dim3(1536/32, 384/32), 256, 0, stream>>>(fc1w,  W1h, W1l, 384, 1536);
    wprep<<<dim3(384/32, 1536/32), 256, 0, stream>>>(fc2w,  W2h, W2l, 1536, 384);

    // 1. LN1 + shift + window partition -> ABh (window-ordered, bf16)
    ln_kernel<true><<<TOKENS, 128, 0, stream>>>(x, n1g, n1b, ABh);

    // 2+3. per-chunk: QKV GEMM (bf16 out) -> region, attention -> ABh (same rows, sequential)
    for (int c = 0; c < 8 / gq; ++c) {
        size_t off = (size_t)c * gq * TPI;
        int M = gq * TPI;
        dim3 g((3 * CC) / 128, M / 128);
        gemm_mfma<EPI_QKV><<<g, 256, 0, stream>>>(
            ABh + off * CC, Wqh, Wql, qkv_b, nullptr, nullptr, region, M, 3 * CC, CC);
        attn2<<<gq * NWIN * HEADS, 64, 0, stream>>>(region, rpb, ABh, c * gq * NWIN);
    }

    // 4. proj GEMM + window reverse + roll + residual -> xr (= d_out)
    {
        dim3 g(CC / 128, TOKENS / 128);
        gemm_mfma<EPI_PROJ><<<g, 256, 0, stream>>>(
            ABh, Wph, Wpl, proj_b, x, xr, nullptr, TOKENS, CC, CC);
    }

    // 5. LN2 -> ABh
    ln_kernel<false><<<TOKENS, 128, 0, stream>>>(xr, n2g, n2b, ABh);

    // 6+7. per-chunk: fc1+GELU -> Hbuf (bf16), fc2 + residual -> d_out
    for (int c = 0; c < 8 / gh; ++c) {
        size_t off = (size_t)c * gh * TPI;
        int M = gh * TPI;
        {
            dim3 g(HID / 128, M / 128);
            gemm_mfma<EPI_GELU><<<g, 256, 0, stream>>>(
                ABh + off * CC, W1h, W1l, fc1b, nullptr, nullptr, Hbuf, M, HID, CC);
        }
        {
            dim3 g(CC / 128, M / 128);
            gemm_mfma<EPI_FC2><<<g, 256, 0, stream>>>(
                Hbuf, W2h, W2l, fc2b, xr + off * CC, (float*)d_out + off * CC, nullptr, M, CC, HID);
        }
    }
}

// Round 5
// 385.213 us; speedup vs baseline: 3.4866x; 1.3834x over previous
//
#include <hip/hip_runtime.h>
#include <hip/hip_bf16.h>
#include <math.h>

#define BD 8
#define HH 56
#define WW 56
#define CC 384
#define HEADS 12
#define HD 32
#define WS 7
#define SS 3
#define NTOK 49
#define NWIN 64            // windows per image (8x8)
#define TOKENS (BD*HH*WW)  // 25088
#define HID 1536
#define TPI (HH*WW)        // tokens per image: 3136

typedef __attribute__((ext_vector_type(8))) short bf16x8;
typedef __attribute__((ext_vector_type(4))) float f32x4;

__device__ __forceinline__ unsigned short f2bf(float f) {
    unsigned int u = __float_as_uint(f);
    unsigned int r = (u + 0x7FFFu + ((u >> 16) & 1u)) >> 16;
    return (unsigned short)r;
}
__device__ __forceinline__ float bf2f(unsigned short h) {
    return __uint_as_float(((unsigned int)h) << 16);
}
__device__ __forceinline__ void gload16(const void* g, void* l) {
    __builtin_amdgcn_global_load_lds((const __attribute__((address_space(1))) unsigned int*)g,
                                     (__attribute__((address_space(3))) unsigned int*)l, 16, 0, 0);
}

// ---------------- Weight prep: W[K][N] fp32 -> Wt_hi[N][K], Wt_lo[N][K] bf16 (transpose+split) ----
__global__ __launch_bounds__(256)
void wprep(const float* __restrict__ W, unsigned short* __restrict__ Th,
           unsigned short* __restrict__ Tl, int K, int N)
{
    __shared__ float t[32][33];
    int n0 = blockIdx.x * 32, k0 = blockIdx.y * 32;
    int c = threadIdx.x & 31, r = threadIdx.x >> 5;   // r: 0..7
    #pragma unroll
    for (int rr = 0; rr < 32; rr += 8)
        t[r + rr][c] = W[(size_t)(k0 + r + rr) * N + n0 + c];
    __syncthreads();
    #pragma unroll
    for (int rr = 0; rr < 32; rr += 8) {
        int i = r + rr;                 // n-local
        float v = t[c][i];              // = W[k0+c][n0+i]
        unsigned short h = f2bf(v);
        Th[(size_t)(n0 + i) * K + k0 + c] = h;
        Tl[(size_t)(n0 + i) * K + k0 + c] = f2bf(v - bf2f(h));
    }
}

// ---------------- bias table: [4 wtype][12 head][64x64] in MFMA acc layout, pre-scaled ----------
__global__ __launch_bounds__(256)
void bias_prep(const float* __restrict__ rpb, float* __restrict__ Bias)
{
    int e = blockIdx.x * 256 + threadIdx.x;      // 196608 total
    int wtq = e / 49152;
    int hr  = e - wtq * 49152;
    int h   = hr >> 12;
    int rem = hr & 4095;
    int jt = rem >> 10, it = (rem >> 8) & 3, lane = (rem >> 2) & 63, reg = rem & 3;
    int j = jt * 16 + ((lane >> 4) << 2) + reg;   // S^T row (= k token)
    int i = it * 16 + (lane & 15);                // S^T col (= q token)
    float val;
    if (j >= NTOK) val = -1e30f;                  // pad columns -> p = 0
    else if (i >= NTOK) val = 0.0f;               // pad q rows, unused
    else {
        int ti = i / 7, tj = i - ti * 7, yj = j / 7, xj = j - yj * 7;
        float b = rpb[((ti - yj + 6) * 13 + (tj - xj + 6)) * HEADS + h];
        int wh7 = wtq >> 1, ww7 = wtq & 1;
        int lhi = wh7 ? (ti < 4 ? 1 : 2) : 0, lhj = wh7 ? (yj < 4 ? 1 : 2) : 0;
        int lwi = ww7 ? (tj < 4 ? 1 : 2) : 0, lwj = ww7 ? (xj < 4 ? 1 : 2) : 0;
        if (lhi != lhj || lwi != lwj) b -= 100.0f;
        val = b * 5.65685424949238f;              // / scale  (scale = 1/sqrt(32))
    }
    Bias[e] = val;
}

// ---------------- zero fill (u32) ----------------
__global__ __launch_bounds__(256)
void zerofill(unsigned int* __restrict__ p, long n)
{
    long i = (long)blockIdx.x * 256 + threadIdx.x;
    long stride = (long)gridDim.x * 256;
    for (; i < n; i += stride) p[i] = 0u;
}

// ---------------- LayerNorm -> bf16 (optionally fused shift+window gather) ----------------
template<bool SHIFT>
__global__ __launch_bounds__(128)
void ln_kernel(const float* __restrict__ in, const float* __restrict__ g,
               const float* __restrict__ beta, unsigned short* __restrict__ oh)
{
    int m = blockIdx.x;
    const float* src;
    size_t dbase = (size_t)m * CC;
    if (SHIFT) {
        int b  = m / (NWIN * NTOK);
        int rr = m % (NWIN * NTOK);
        int w  = rr / NTOK;
        int t  = rr % NTOK;
        int wh = w >> 3, ww = w & 7;
        int ti = t / 7,  tj = t - (t / 7) * 7;
        int hh = wh * WS + ti + SS;  if (hh >= HH) hh -= HH;
        int w2 = ww * WS + tj + SS;  if (w2 >= WW) w2 -= WW;
        src = in + ((size_t)b * TPI + hh * WW + w2) * CC;
    } else {
        src = in + (size_t)m * CC;
    }
    int tid = threadIdx.x;
    float v0 = src[tid], v1 = src[tid + 128], v2 = src[tid + 256];
    float s  = v0 + v1 + v2;
    float ss = v0*v0 + v1*v1 + v2*v2;
    #pragma unroll
    for (int off = 32; off > 0; off >>= 1) {
        s  += __shfl_down(s, off);
        ss += __shfl_down(ss, off);
    }
    __shared__ float red[4];
    int wid = tid >> 6, lane = tid & 63;
    if (lane == 0) { red[wid] = s; red[wid + 2] = ss; }
    __syncthreads();
    float tot   = red[0] + red[1];
    float totss = red[2] + red[3];
    float mu   = tot * (1.0f / CC);
    float var  = totss * (1.0f / CC) - mu * mu;
    float rstd = rsqrtf(var + 1e-5f);
    #pragma unroll
    for (int e = 0; e < 3; ++e) {
        int idx = tid + e * 128;
        float v = (e == 0 ? v0 : (e == 1 ? v1 : v2));
        float y = (v - mu) * rstd * g[idx] + beta[idx];
        oh[dbase + idx] = f2bf(y);
    }
}

// ---------------- 2-pass split-bf16 MFMA GEMM: 128x128 tile, BK=32, 4 waves ----------------
#define EPI_QKV  0   // Q,K -> QKb [tok][768]; V -> Vtg [384][cw*64] transposed win-padded
#define EPI_GELU 1   // outh = bf16(gelu(acc + bias))           (fc1)
#define EPI_PROJ 2   // outf[pix] = extra[pix] + acc + bias     (proj + window-reverse + roll + residual)
#define EPI_FC2  3   // outf = extra + acc + bias               (fc2 + residual)

template<int EPI>
__global__ __launch_bounds__(256)
void gemm_mfma(const unsigned short* __restrict__ Ah,
               const unsigned short* __restrict__ Bh, const unsigned short* __restrict__ Bl,
               const float* __restrict__ bias, const float* __restrict__ extra,
               float* __restrict__ outf, unsigned short* __restrict__ outh,
               unsigned short* __restrict__ vtg, int vstride,
               int M, int N, int K)
{
    __shared__ unsigned short lds[3][128][32];

    int tid  = threadIdx.x;
    int lane = tid & 63;
    int wave = tid >> 6;
    int wr = wave >> 1, wc = wave & 1;
    int m0 = blockIdx.y * 128, n0 = blockIdx.x * 128;

    int lrow = lane >> 2;      // staging row within 16-row chunk
    int ps   = lane & 3;       // staging 16B slot
    int kslot = lane >> 4;     // frag k-chunk
    int rA    = lane & 15;     // frag row/col

    f32x4 acc[4][4];
    #pragma unroll
    for (int i = 0; i < 4; ++i)
        #pragma unroll
        for (int j = 0; j < 4; ++j)
            acc[i][j] = (f32x4){0.f, 0.f, 0.f, 0.f};

    for (int k0 = 0; k0 < K; k0 += 32) {
        #pragma unroll
        for (int s = 0; s < 6; ++s) {
            int seg = wave * 6 + s;          // 0..23
            int bf = seg >> 3, c = seg & 7;
            const unsigned short* gb = (bf == 0) ? Ah : (bf == 1) ? Bh : Bl;
            int r0 = (bf == 0) ? m0 : n0;
            int row = c * 16 + lrow;
            int ks = ps ^ ((row >> 1) & 3);
            gload16(gb + (size_t)(r0 + row) * K + k0 + ks * 8, &lds[bf][c * 16][0]);
        }
        __syncthreads();

        bf16x8 ah[4], bh[4], bl[4];
        #pragma unroll
        for (int f = 0; f < 4; ++f) {
            int row = wr * 64 + f * 16 + rA;
            int p = (kslot ^ ((row >> 1) & 3)) * 8;
            ah[f] = *(const bf16x8*)&lds[0][row][p];
            int col = wc * 64 + f * 16 + rA;
            int pb = (kslot ^ ((col >> 1) & 3)) * 8;
            bh[f] = *(const bf16x8*)&lds[1][col][pb];
            bl[f] = *(const bf16x8*)&lds[2][col][pb];
        }
        #pragma unroll
        for (int i = 0; i < 4; ++i)
            #pragma unroll
            for (int j = 0; j < 4; ++j)
                acc[i][j] = __builtin_amdgcn_mfma_f32_16x16x32_bf16(ah[i], bh[j], acc[i][j], 0, 0, 0);
        #pragma unroll
        for (int i = 0; i < 4; ++i)
            #pragma unroll
            for (int j = 0; j < 4; ++j)
                acc[i][j] = __builtin_amdgcn_mfma_f32_16x16x32_bf16(ah[i], bl[j], acc[i][j], 0, 0, 0);
        __syncthreads();
    }

    int cn = lane & 15;
    int rb = (lane >> 4) * 4;
    float bj[4];
    #pragma unroll
    for (int j = 0; j < 4; ++j) bj[j] = bias[n0 + wc * 64 + j * 16 + cn];
    int ncol = n0 + wc * 64 + cn;

    #pragma unroll
    for (int i = 0; i < 4; ++i) {
        #pragma unroll
        for (int r = 0; r < 4; ++r) {
            int mg = m0 + wr * 64 + i * 16 + rb + r;
            if (EPI == EPI_QKV) {
                if (n0 < 768) {
                    unsigned short* orow = outh + (size_t)mg * 768 + ncol;
                    #pragma unroll
                    for (int j = 0; j < 4; ++j) orow[j * 16] = f2bf(acc[i][j][r] + bj[j]);
                } else {
                    int win = mg / NTOK;
                    int t   = mg - win * NTOK;
                    #pragma unroll
                    for (int j = 0; j < 4; ++j) {
                        int c = ncol + j * 16 - 768;    // 0..383 = head*32+d
                        vtg[(size_t)c * vstride + win * 64 + t] = f2bf(acc[i][j][r] + bj[j]);
                    }
                }
            } else if (EPI == EPI_GELU) {
                unsigned short* orow = outh + (size_t)mg * N + ncol;
                #pragma unroll
                for (int j = 0; j < 4; ++j) {
                    float t = acc[i][j][r] + bj[j];
                    float gl = 0.5f * t * (1.0f + erff(t * 0.70710678118654752f));
                    orow[j * 16] = f2bf(gl);
                }
            } else if (EPI == EPI_PROJ) {
                int b  = mg / (NWIN * NTOK);
                int rr = mg % (NWIN * NTOK);
                int w  = rr / NTOK;
                int t  = rr % NTOK;
                int wh = w >> 3, ww = w & 7;
                int ti = t / 7,  tj = t - (t / 7) * 7;
                int hh = wh * WS + ti + SS;  if (hh >= HH) hh -= HH;
                int w2 = ww * WS + tj + SS;  if (w2 >= WW) w2 -= WW;
                size_t pix = (size_t)b * TPI + hh * WW + w2;
                const float* xin = extra + pix * CC + ncol;
                float* xo = outf + pix * CC + ncol;
                #pragma unroll
                for (int j = 0; j < 4; ++j) xo[j * 16] = xin[j * 16] + acc[i][j][r] + bj[j];
            } else { // EPI_FC2
                const float* xi = extra + (size_t)mg * N + ncol;
                float* xo = outf + (size_t)mg * N + ncol;
                #pragma unroll
                for (int j = 0; j < 4; ++j) xo[j * 16] = xi[j * 16] + acc[i][j][r] + bj[j];
            }
        }
    }
}

// ---------------- Attention v3: MFMA, one wave per (window, head) ----------------
// QKb: [chunkTok][768] bf16 (Q|K). Vtg: [384][chunkWin*64] bf16 transposed, win-padded, pads zero.
// Bias: [4][12][4096] f32 in acc layout (bias+mask, pre-divided by scale; pad cols -1e30).
__global__ __launch_bounds__(256)
void attn3(const unsigned short* __restrict__ QKb, const unsigned short* __restrict__ Vtg,
           const float* __restrict__ Bias, unsigned short* __restrict__ outh,
           int vstride, int win0)
{
    int wave = threadIdx.x >> 6, lane = threadIdx.x & 63;
    int unit = blockIdx.x * 4 + wave;
    int head = unit % HEADS;
    int winl = unit / HEADS;
    int wing = win0 + winl;
    int wl   = wing & (NWIN - 1);
    int wt   = (((wl >> 3) == 7) << 1) | ((wl & 7) == 7);
    int qbase = winl * NTOK;
    size_t obase = (size_t)wing * NTOK;

    __shared__ __align__(16) unsigned short Pl_all[4][64][64];
    unsigned short (*Pl)[64] = Pl_all[wave];

    int l15 = lane & 15, g = lane >> 4;

    // ---- K/Q fragments straight from global (row-clamped) ----
    bf16x8 kf[4], qf[4];
    #pragma unroll
    for (int t = 0; t < 4; ++t) {
        int rr = t * 16 + l15; if (rr > NTOK - 1) rr = NTOK - 1;
        const unsigned short* base = QKb + (size_t)(qbase + rr) * 768 + head * HD + g * 8;
        qf[t] = *(const bf16x8*)base;
        kf[t] = *(const bf16x8*)(base + 384);
    }

    // ---- S^T = K·Q^T + bias (C-init from table) ----
    const float* bb = Bias + (((size_t)wt * HEADS + head) << 12);
    f32x4 acc[4][4];   // [jt][it]
    #pragma unroll
    for (int jt = 0; jt < 4; ++jt)
        #pragma unroll
        for (int it = 0; it < 4; ++it) {
            f32x4 c = *(const f32x4*)(bb + ((jt * 4 + it) * 64 + lane) * 4);
            acc[jt][it] = __builtin_amdgcn_mfma_f32_16x16x32_bf16(kf[jt], qf[it], c, 0, 0, 0);
        }

    // ---- softmax over j (lane-local per column i), P -> LDS (bf16, XOR-swizzled) ----
    const float K1 = 0.25503488f;   // scale * log2(e)
    #pragma unroll
    for (int jt = 0; jt < 4; ++jt)
        #pragma unroll
        for (int it = 0; it < 4; ++it)
            #pragma unroll
            for (int r = 0; r < 4; ++r)
                acc[jt][it][r] = exp2f(acc[jt][it][r] * K1);

    #pragma unroll
    for (int it = 0; it < 4; ++it) {
        float s = 0.0f;
        #pragma unroll
        for (int jt = 0; jt < 4; ++jt)
            s += (acc[jt][it][0] + acc[jt][it][1]) + (acc[jt][it][2] + acc[jt][it][3]);
        s += __shfl_xor(s, 16);
        s += __shfl_xor(s, 32);
        float inv = 1.0f / s;
        int i  = it * 16 + l15;
        int sw = (i & 7) << 3;
        #pragma unroll
        for (int jt = 0; jt < 4; ++jt) {
            float a0 = acc[jt][it][0] * inv, a1 = acc[jt][it][1] * inv;
            float a2 = acc[jt][it][2] * inv, a3 = acc[jt][it][3] * inv;
            unsigned int w0, w1;
            asm("v_cvt_pk_bf16_f32 %0, %1, %2" : "=v"(w0) : "v"(a0), "v"(a1));
            asm("v_cvt_pk_bf16_f32 %0, %1, %2" : "=v"(w1) : "v"(a2), "v"(a3));
            int js = (jt * 16 + g * 4) ^ sw;
            *(unsigned int*)&Pl[i][js]     = w0;
            *(unsigned int*)&Pl[i][js + 2] = w1;
        }
    }

    // ---- O = P·V ----
    bf16x8 vf[2][2];
    #pragma unroll
    for (int dt = 0; dt < 2; ++dt)
        #pragma unroll
        for (int kc = 0; kc < 2; ++kc)
            vf[dt][kc] = *(const bf16x8*)(Vtg + (size_t)(head * HD + dt * 16 + l15) * vstride
                                          + winl * 64 + kc * 32 + g * 8);
    f32x4 oacc[4][2];
    #pragma unroll
    for (int it = 0; it < 4; ++it)
        #pragma unroll
        for (int dt = 0; dt < 2; ++dt)
            oacc[it][dt] = (f32x4){0.f, 0.f, 0.f, 0.f};

    #pragma unroll
    for (int it = 0; it < 4; ++it) {
        int i  = it * 16 + l15;
        int sw = (i & 7) << 3;
        #pragma unroll
        for (int kc = 0; kc < 2; ++kc) {
            int js = (kc * 32 + g * 8) ^ sw;
            bf16x8 pf = *(const bf16x8*)&Pl[i][js];
            #pragma unroll
            for (int dt = 0; dt < 2; ++dt)
                oacc[it][dt] = __builtin_amdgcn_mfma_f32_16x16x32_bf16(pf, vf[dt][kc], oacc[it][dt], 0, 0, 0);
        }
    }

    // ---- store O rows (i < 49) ----
    #pragma unroll
    for (int it = 0; it < 4; ++it) {
        #pragma unroll
        for (int r = 0; r < 4; ++r) {
            int i = it * 16 + g * 4 + r;
            if (i < NTOK) {
                unsigned short* orow = outh + (obase + i) * CC + head * HD;
                orow[l15]      = f2bf(oacc[it][0][r]);
                orow[16 + l15] = f2bf(oacc[it][1][r]);
            }
        }
    }
}

// ---------------- launcher ----------------
extern "C" void kernel_launch(void* const* d_in, const int* in_sizes, int n_in,
                              void* d_out, int out_size, void* d_ws, size_t ws_size,
                              hipStream_t stream)
{
    const float* x      = (const float*)d_in[0];
    const float* qkv_w  = (const float*)d_in[2];
    const float* qkv_b  = (const float*)d_in[3];
    const float* proj_w = (const float*)d_in[4];
    const float* proj_b = (const float*)d_in[5];
    const float* rpb    = (const float*)d_in[6];
    const float* n1g    = (const float*)d_in[7];
    const float* n1b    = (const float*)d_in[8];
    const float* n2g    = (const float*)d_in[9];
    const float* n2b    = (const float*)d_in[10];
    const float* fc1w   = (const float*)d_in[11];
    const float* fc1b   = (const float*)d_in[12];
    const float* fc2w   = (const float*)d_in[13];
    const float* fc2b   = (const float*)d_in[14];

    float* xr = (float*)d_out;                     // d_out doubles as xr residual buffer

    // ---- workspace carve-up ----
    unsigned short* p = (unsigned short*)d_ws;
    unsigned short* Wqh = p; p += 442368;  unsigned short* Wql = p; p += 442368;
    unsigned short* Wph = p; p += 147456;  unsigned short* Wpl = p; p += 147456;
    unsigned short* W1h = p; p += 589824;  unsigned short* W1l = p; p += 589824;
    unsigned short* W2h = p; p += 589824;  unsigned short* W2l = p; p += 589824;
    unsigned short* ABh = p; p += (size_t)TOKENS * CC;
    float* Bias = (float*)p;                       // 196608 f32
    unsigned short* region = (unsigned short*)(Bias + 196608);
    unsigned short* Hbuf = region;

    const size_t FIXED = 27131904;                 // bytes before region
    size_t R = (ws_size > FIXED) ? ws_size - FIXED : 0;
    int gq = 2;                                    // images per qkv chunk
    if (R >= (size_t)8 * 7962624)      gq = 8;
    else if (R >= (size_t)4 * 7962624) gq = 4;
    int gh = 2;                                    // images per MLP chunk
    if (R >= (size_t)8 * TPI * HID * 2)      gh = 8;
    else if (R >= (size_t)4 * TPI * HID * 2) gh = 4;

    unsigned short* QKb = region;
    unsigned short* Vtg = region + (size_t)gq * TPI * 768;   // [384][gq*4096]
    int vstride = gq * NWIN * 64;                  // tokens per d-row (win-padded)

    // 0. tables + weight prep + V pad zeroing
    bias_prep<<<768, 256, 0, stream>>>(rpb, Bias);
    wprep<<<dim3(1152/32, 384/32), 256, 0, stream>>>(qkv_w, Wqh, Wql, 384, 1152);
    wprep<<<dim3(384/32,  384/32), 256, 0, stream>>>(proj_w, Wph, Wpl, 384, 384);
    wprep<<<dim3(1536/32, 384/32), 256, 0, stream>>>(fc1w,  W1h, W1l, 384, 1536);
    wprep<<<dim3(384/32, 1536/32), 256, 0, stream>>>(fc2w,  W2h, W2l, 1536, 384);
    zerofill<<<2048, 256, 0, stream>>>((unsigned int*)Vtg, (long)384 * vstride / 2);

    // 1. LN1 + shift + window partition -> ABh (window-ordered, bf16)
    ln_kernel<true><<<TOKENS, 128, 0, stream>>>(x, n1g, n1b, ABh);

    // 2+3. per-chunk: QKV GEMM -> QKb/Vtg, MFMA attention -> ABh
    for (int c = 0; c < 8 / gq; ++c) {
        size_t off = (size_t)c * gq * TPI;
        int M = gq * TPI;
        dim3 gmm((3 * CC) / 128, M / 128);
        gemm_mfma<EPI_QKV><<<gmm, 256, 0, stream>>>(
            ABh + off * CC, Wqh, Wql, qkv_b, nullptr, nullptr, QKb, Vtg, vstride, M, 3 * CC, CC);
        attn3<<<gq * NWIN * HEADS / 4, 256, 0, stream>>>(
            QKb, Vtg, Bias, ABh, vstride, c * gq * NWIN);
    }

    // 4. proj GEMM + window reverse + roll + residual -> xr (= d_out)
    {
        dim3 gmm(CC / 128, TOKENS / 128);
        gemm_mfma<EPI_PROJ><<<gmm, 256, 0, stream>>>(
            ABh, Wph, Wpl, proj_b, x, xr, nullptr, nullptr, 0, TOKENS, CC, CC);
    }

    // 5. LN2 -> ABh
    ln_kernel<false><<<TOKENS, 128, 0, stream>>>(xr, n2g, n2b, ABh);

    // 6+7. per-chunk: fc1+GELU -> Hbuf (bf16), fc2 + residual -> d_out
    for (int c = 0; c < 8 / gh; ++c) {
        size_t off = (size_t)c * gh * TPI;
        int M = gh * TPI;
        {
            dim3 gmm(HID / 128, M / 128);
            gemm_mfma<EPI_GELU><<<gmm, 256, 0, stream>>>(
                ABh + off * CC, W1h, W1l, fc1b, nullptr, nullptr, Hbuf, nullptr, 0, M, HID, CC);
        }
        {
            dim3 gmm(CC / 128, M / 128);
            gemm_mfma<EPI_FC2><<<gmm, 256, 0, stream>>>(
                Hbuf, W2h, W2l, fc2b, xr + off * CC, (float*)d_out + off * CC, nullptr, nullptr, 0, M, CC, HID);
        }
    }
}

// Round 6
// 352.348 us; speedup vs baseline: 3.8118x; 1.0933x over previous
//
#include <hip/hip_runtime.h>
#include <hip/hip_bf16.h>
#include <math.h>

#define BD 8
#define HH 56
#define WW 56
#define CC 384
#define HEADS 12
#define HD 32
#define WS 7
#define SS 3
#define NTOK 49
#define NWIN 64            // windows per image (8x8)
#define TOKENS (BD*HH*WW)  // 25088
#define HID 1536
#define TPI (HH*WW)        // tokens per image: 3136

typedef __attribute__((ext_vector_type(8))) short bf16x8;
typedef __attribute__((ext_vector_type(4))) float f32x4;

__device__ __forceinline__ unsigned short f2bf(float f) {
    unsigned int u = __float_as_uint(f);
    unsigned int r = (u + 0x7FFFu + ((u >> 16) & 1u)) >> 16;
    return (unsigned short)r;
}
__device__ __forceinline__ float bf2f(unsigned short h) {
    return __uint_as_float(((unsigned int)h) << 16);
}
__device__ __forceinline__ void gload16(const void* g, void* l) {
    __builtin_amdgcn_global_load_lds((const __attribute__((address_space(1))) unsigned int*)g,
                                     (__attribute__((address_space(3))) unsigned int*)l, 16, 0, 0);
}

// ---------------- Weight prep: W[K][N] fp32 -> Wt_hi[N][K], Wt_lo[N][K] bf16 (transpose+split) ----
__global__ __launch_bounds__(256)
void wprep(const float* __restrict__ W, unsigned short* __restrict__ Th,
           unsigned short* __restrict__ Tl, int K, int N)
{
    __shared__ float t[32][33];
    int n0 = blockIdx.x * 32, k0 = blockIdx.y * 32;
    int c = threadIdx.x & 31, r = threadIdx.x >> 5;   // r: 0..7
    #pragma unroll
    for (int rr = 0; rr < 32; rr += 8)
        t[r + rr][c] = W[(size_t)(k0 + r + rr) * N + n0 + c];
    __syncthreads();
    #pragma unroll
    for (int rr = 0; rr < 32; rr += 8) {
        int i = r + rr;                 // n-local
        float v = t[c][i];              // = W[k0+c][n0+i]
        unsigned short h = f2bf(v);
        Th[(size_t)(n0 + i) * K + k0 + c] = h;
        Tl[(size_t)(n0 + i) * K + k0 + c] = f2bf(v - bf2f(h));
    }
}

// ---------------- bias table: [4 wtype][12 head][64x64] in MFMA acc layout, pre-scaled ----------
__global__ __launch_bounds__(256)
void bias_prep(const float* __restrict__ rpb, float* __restrict__ Bias)
{
    int e = blockIdx.x * 256 + threadIdx.x;      // 196608 total
    int wtq = e / 49152;
    int hr  = e - wtq * 49152;
    int h   = hr >> 12;
    int rem = hr & 4095;
    int jt = rem >> 10, it = (rem >> 8) & 3, lane = (rem >> 2) & 63, reg = rem & 3;
    int j = jt * 16 + ((lane >> 4) << 2) + reg;   // S^T row (= k token)
    int i = it * 16 + (lane & 15);                // S^T col (= q token)
    float val;
    if (j >= NTOK) val = -1e30f;                  // pad columns -> p = 0
    else if (i >= NTOK) val = 0.0f;               // pad q rows, unused
    else {
        int ti = i / 7, tj = i - ti * 7, yj = j / 7, xj = j - yj * 7;
        float b = rpb[((ti - yj + 6) * 13 + (tj - xj + 6)) * HEADS + h];
        int wh7 = wtq >> 1, ww7 = wtq & 1;
        int lhi = wh7 ? (ti < 4 ? 1 : 2) : 0, lhj = wh7 ? (yj < 4 ? 1 : 2) : 0;
        int lwi = ww7 ? (tj < 4 ? 1 : 2) : 0, lwj = ww7 ? (xj < 4 ? 1 : 2) : 0;
        if (lhi != lhj || lwi != lwj) b -= 100.0f;
        val = b * 5.65685424949238f;              // / scale  (scale = 1/sqrt(32))
    }
    Bias[e] = val;
}

// ---------------- zero fill (u32) ----------------
__global__ __launch_bounds__(256)
void zerofill(unsigned int* __restrict__ p, long n)
{
    long i = (long)blockIdx.x * 256 + threadIdx.x;
    long stride = (long)gridDim.x * 256;
    for (; i < n; i += stride) p[i] = 0u;
}

// ---------------- LayerNorm -> bf16 (optionally fused shift+window gather) ----------------
template<bool SHIFT>
__global__ __launch_bounds__(128)
void ln_kernel(const float* __restrict__ in, const float* __restrict__ g,
               const float* __restrict__ beta, unsigned short* __restrict__ oh)
{
    int m = blockIdx.x;
    const float* src;
    size_t dbase = (size_t)m * CC;
    if (SHIFT) {
        int b  = m / (NWIN * NTOK);
        int rr = m % (NWIN * NTOK);
        int w  = rr / NTOK;
        int t  = rr % NTOK;
        int wh = w >> 3, ww = w & 7;
        int ti = t / 7,  tj = t - (t / 7) * 7;
        int hh = wh * WS + ti + SS;  if (hh >= HH) hh -= HH;
        int w2 = ww * WS + tj + SS;  if (w2 >= WW) w2 -= WW;
        src = in + ((size_t)b * TPI + hh * WW + w2) * CC;
    } else {
        src = in + (size_t)m * CC;
    }
    int tid = threadIdx.x;
    float v0 = src[tid], v1 = src[tid + 128], v2 = src[tid + 256];
    float s  = v0 + v1 + v2;
    float ss = v0*v0 + v1*v1 + v2*v2;
    #pragma unroll
    for (int off = 32; off > 0; off >>= 1) {
        s  += __shfl_down(s, off);
        ss += __shfl_down(ss, off);
    }
    __shared__ float red[4];
    int wid = tid >> 6, lane = tid & 63;
    if (lane == 0) { red[wid] = s; red[wid + 2] = ss; }
    __syncthreads();
    float tot   = red[0] + red[1];
    float totss = red[2] + red[3];
    float mu   = tot * (1.0f / CC);
    float var  = totss * (1.0f / CC) - mu * mu;
    float rstd = rsqrtf(var + 1e-5f);
    #pragma unroll
    for (int e = 0; e < 3; ++e) {
        int idx = tid + e * 128;
        float v = (e == 0 ? v0 : (e == 1 ? v1 : v2));
        float y = (v - mu) * rstd * g[idx] + beta[idx];
        oh[dbase + idx] = f2bf(y);
    }
}

// ---------------- 2-pass split-bf16 MFMA GEMM: 128x128 tile, BK=32, WAVES=4 or 8 ----------------
// WAVES=4: wave computes 64x64 (acc[4][4]).  WAVES=8: wave computes 64x32 (acc[4][2]) —
// for grid-starved shapes (N=384 -> 588 blocks), 8-wave blocks double waves/CU.
#define EPI_QKV  0   // Q,K -> QKb [tok][768]; V -> Vtg [384][cw*64] transposed win-padded
#define EPI_GELU 1   // outh = bf16(gelu(acc + bias))           (fc1)
#define EPI_PROJ 2   // outf[pix] = extra[pix] + acc + bias     (proj + window-reverse + roll + residual)
#define EPI_FC2  3   // outf = extra + acc + bias               (fc2 + residual)

template<int EPI, int WAVES>
__global__ __launch_bounds__(WAVES * 64)
void gemm_mfma(const unsigned short* __restrict__ Ah,
               const unsigned short* __restrict__ Bh, const unsigned short* __restrict__ Bl,
               const float* __restrict__ bias, const float* __restrict__ extra,
               float* __restrict__ outf, unsigned short* __restrict__ outh,
               unsigned short* __restrict__ vtg, int vstride,
               int M, int N, int K)
{
    constexpr int PER = 24 / WAVES;      // staging segments per wave
    constexpr int CF  = 16 / WAVES;      // column fragments per wave (4 or 2)
    __shared__ unsigned short lds[3][128][32];

    int tid  = threadIdx.x;
    int lane = tid & 63;
    int wave = tid >> 6;
    int wr = (WAVES == 4) ? (wave >> 1) : (wave >> 2);
    int wc = (WAVES == 4) ? (wave & 1)  : (wave & 3);
    int m0 = blockIdx.y * 128, n0 = blockIdx.x * 128;

    int lrow = lane >> 2;      // staging row within 16-row chunk
    int ps   = lane & 3;       // staging 16B slot
    int kslot = lane >> 4;     // frag k-chunk
    int rA    = lane & 15;     // frag row/col

    f32x4 acc[4][CF];
    #pragma unroll
    for (int i = 0; i < 4; ++i)
        #pragma unroll
        for (int j = 0; j < CF; ++j)
            acc[i][j] = (f32x4){0.f, 0.f, 0.f, 0.f};

    for (int k0 = 0; k0 < K; k0 += 32) {
        #pragma unroll
        for (int s = 0; s < PER; ++s) {
            int seg = wave * PER + s;        // 0..23
            int bf = seg >> 3, c = seg & 7;
            const unsigned short* gb = (bf == 0) ? Ah : (bf == 1) ? Bh : Bl;
            int r0 = (bf == 0) ? m0 : n0;
            int row = c * 16 + lrow;
            int ks = ps ^ ((row >> 1) & 3);
            gload16(gb + (size_t)(r0 + row) * K + k0 + ks * 8, &lds[bf][c * 16][0]);
        }
        __syncthreads();

        bf16x8 ah[4], bh[CF], bl[CF];
        #pragma unroll
        for (int f = 0; f < 4; ++f) {
            int row = wr * 64 + f * 16 + rA;
            int p = (kslot ^ ((row >> 1) & 3)) * 8;
            ah[f] = *(const bf16x8*)&lds[0][row][p];
        }
        #pragma unroll
        for (int f = 0; f < CF; ++f) {
            int col = wc * (CF * 16) + f * 16 + rA;
            int pb = (kslot ^ ((col >> 1) & 3)) * 8;
            bh[f] = *(const bf16x8*)&lds[1][col][pb];
            bl[f] = *(const bf16x8*)&lds[2][col][pb];
        }
        #pragma unroll
        for (int i = 0; i < 4; ++i)
            #pragma unroll
            for (int j = 0; j < CF; ++j)
                acc[i][j] = __builtin_amdgcn_mfma_f32_16x16x32_bf16(ah[i], bh[j], acc[i][j], 0, 0, 0);
        #pragma unroll
        for (int i = 0; i < 4; ++i)
            #pragma unroll
            for (int j = 0; j < CF; ++j)
                acc[i][j] = __builtin_amdgcn_mfma_f32_16x16x32_bf16(ah[i], bl[j], acc[i][j], 0, 0, 0);
        __syncthreads();
    }

    int cn = lane & 15;
    int rb = (lane >> 4) * 4;
    float bj[CF];
    #pragma unroll
    for (int j = 0; j < CF; ++j) bj[j] = bias[n0 + wc * (CF * 16) + j * 16 + cn];
    int ncol = n0 + wc * (CF * 16) + cn;

    #pragma unroll
    for (int i = 0; i < 4; ++i) {
        #pragma unroll
        for (int r = 0; r < 4; ++r) {
            int mg = m0 + wr * 64 + i * 16 + rb + r;
            if (EPI == EPI_QKV) {
                if (n0 < 768) {
                    unsigned short* orow = outh + (size_t)mg * 768 + ncol;
                    #pragma unroll
                    for (int j = 0; j < CF; ++j) orow[j * 16] = f2bf(acc[i][j][r] + bj[j]);
                } else {
                    int win = mg / NTOK;
                    int t   = mg - win * NTOK;
                    #pragma unroll
                    for (int j = 0; j < CF; ++j) {
                        int c = ncol + j * 16 - 768;    // 0..383 = head*32+d
                        vtg[(size_t)c * vstride + win * 64 + t] = f2bf(acc[i][j][r] + bj[j]);
                    }
                }
            } else if (EPI == EPI_GELU) {
                unsigned short* orow = outh + (size_t)mg * N + ncol;
                #pragma unroll
                for (int j = 0; j < CF; ++j) {
                    float t = acc[i][j][r] + bj[j];
                    float gl = 0.5f * t * (1.0f + erff(t * 0.70710678118654752f));
                    orow[j * 16] = f2bf(gl);
                }
            } else if (EPI == EPI_PROJ) {
                int b  = mg / (NWIN * NTOK);
                int rr = mg % (NWIN * NTOK);
                int w  = rr / NTOK;
                int t  = rr % NTOK;
                int wh = w >> 3, ww = w & 7;
                int ti = t / 7,  tj = t - (t / 7) * 7;
                int hh = wh * WS + ti + SS;  if (hh >= HH) hh -= HH;
                int w2 = ww * WS + tj + SS;  if (w2 >= WW) w2 -= WW;
                size_t pix = (size_t)b * TPI + hh * WW + w2;
                const float* xin = extra + pix * CC + ncol;
                float* xo = outf + pix * CC + ncol;
                #pragma unroll
                for (int j = 0; j < CF; ++j) xo[j * 16] = xin[j * 16] + acc[i][j][r] + bj[j];
            } else { // EPI_FC2
                const float* xi = extra + (size_t)mg * N + ncol;
                float* xo = outf + (size_t)mg * N + ncol;
                #pragma unroll
                for (int j = 0; j < CF; ++j) xo[j * 16] = xi[j * 16] + acc[i][j][r] + bj[j];
            }
        }
    }
}

// ---------------- Attention v3: MFMA, one wave per (window, head) ----------------
// QKb: [chunkTok][768] bf16 (Q|K). Vtg: [384][chunkWin*64] bf16 transposed, win-padded, pads zero.
// Bias: [4][12][4096] f32 in acc layout (bias+mask, pre-divided by scale; pad cols -1e30).
__global__ __launch_bounds__(256)
void attn3(const unsigned short* __restrict__ QKb, const unsigned short* __restrict__ Vtg,
           const float* __restrict__ Bias, unsigned short* __restrict__ outh,
           int vstride, int win0)
{
    int wave = threadIdx.x >> 6, lane = threadIdx.x & 63;
    int unit = blockIdx.x * 4 + wave;
    int head = unit % HEADS;
    int winl = unit / HEADS;
    int wing = win0 + winl;
    int wl   = wing & (NWIN - 1);
    int wt   = (((wl >> 3) == 7) << 1) | ((wl & 7) == 7);
    int qbase = winl * NTOK;
    size_t obase = (size_t)wing * NTOK;

    __shared__ __align__(16) unsigned short Pl_all[4][64][64];
    unsigned short (*Pl)[64] = Pl_all[wave];

    int l15 = lane & 15, g = lane >> 4;

    // ---- K/Q fragments straight from global (row-clamped) ----
    bf16x8 kf[4], qf[4];
    #pragma unroll
    for (int t = 0; t < 4; ++t) {
        int rr = t * 16 + l15; if (rr > NTOK - 1) rr = NTOK - 1;
        const unsigned short* base = QKb + (size_t)(qbase + rr) * 768 + head * HD + g * 8;
        qf[t] = *(const bf16x8*)base;
        kf[t] = *(const bf16x8*)(base + 384);
    }

    // ---- S^T = K·Q^T + bias (C-init from table) ----
    const float* bb = Bias + (((size_t)wt * HEADS + head) << 12);
    f32x4 acc[4][4];   // [jt][it]
    #pragma unroll
    for (int jt = 0; jt < 4; ++jt)
        #pragma unroll
        for (int it = 0; it < 4; ++it) {
            f32x4 c = *(const f32x4*)(bb + ((jt * 4 + it) * 64 + lane) * 4);
            acc[jt][it] = __builtin_amdgcn_mfma_f32_16x16x32_bf16(kf[jt], qf[it], c, 0, 0, 0);
        }

    // ---- softmax over j (lane-local per column i), P -> LDS (bf16, XOR-swizzled) ----
    const float K1 = 0.25503488f;   // scale * log2(e)
    #pragma unroll
    for (int jt = 0; jt < 4; ++jt)
        #pragma unroll
        for (int it = 0; it < 4; ++it)
            #pragma unroll
            for (int r = 0; r < 4; ++r)
                acc[jt][it][r] = exp2f(acc[jt][it][r] * K1);

    #pragma unroll
    for (int it = 0; it < 4; ++it) {
        float s = 0.0f;
        #pragma unroll
        for (int jt = 0; jt < 4; ++jt)
            s += (acc[jt][it][0] + acc[jt][it][1]) + (acc[jt][it][2] + acc[jt][it][3]);
        s += __shfl_xor(s, 16);
        s += __shfl_xor(s, 32);
        float inv = 1.0f / s;
        int i  = it * 16 + l15;
        int sw = (i & 7) << 3;
        #pragma unroll
        for (int jt = 0; jt < 4; ++jt) {
            float a0 = acc[jt][it][0] * inv, a1 = acc[jt][it][1] * inv;
            float a2 = acc[jt][it][2] * inv, a3 = acc[jt][it][3] * inv;
            unsigned int w0, w1;
            asm("v_cvt_pk_bf16_f32 %0, %1, %2" : "=v"(w0) : "v"(a0), "v"(a1));
            asm("v_cvt_pk_bf16_f32 %0, %1, %2" : "=v"(w1) : "v"(a2), "v"(a3));
            int js = (jt * 16 + g * 4) ^ sw;
            *(unsigned int*)&Pl[i][js]     = w0;
            *(unsigned int*)&Pl[i][js + 2] = w1;
        }
    }

    // ---- O = P·V ----
    bf16x8 vf[2][2];
    #pragma unroll
    for (int dt = 0; dt < 2; ++dt)
        #pragma unroll
        for (int kc = 0; kc < 2; ++kc)
            vf[dt][kc] = *(const bf16x8*)(Vtg + (size_t)(head * HD + dt * 16 + l15) * vstride
                                          + winl * 64 + kc * 32 + g * 8);
    f32x4 oacc[4][2];
    #pragma unroll
    for (int it = 0; it < 4; ++it)
        #pragma unroll
        for (int dt = 0; dt < 2; ++dt)
            oacc[it][dt] = (f32x4){0.f, 0.f, 0.f, 0.f};

    #pragma unroll
    for (int it = 0; it < 4; ++it) {
        int i  = it * 16 + l15;
        int sw = (i & 7) << 3;
        #pragma unroll
        for (int kc = 0; kc < 2; ++kc) {
            int js = (kc * 32 + g * 8) ^ sw;
            bf16x8 pf = *(const bf16x8*)&Pl[i][js];
            #pragma unroll
            for (int dt = 0; dt < 2; ++dt)
                oacc[it][dt] = __builtin_amdgcn_mfma_f32_16x16x32_bf16(pf, vf[dt][kc], oacc[it][dt], 0, 0, 0);
        }
    }

    // ---- store O rows (i < 49) ----
    #pragma unroll
    for (int it = 0; it < 4; ++it) {
        #pragma unroll
        for (int r = 0; r < 4; ++r) {
            int i = it * 16 + g * 4 + r;
            if (i < NTOK) {
                unsigned short* orow = outh + (obase + i) * CC + head * HD;
                orow[l15]      = f2bf(oacc[it][0][r]);
                orow[16 + l15] = f2bf(oacc[it][1][r]);
            }
        }
    }
}

// ---------------- launcher ----------------
extern "C" void kernel_launch(void* const* d_in, const int* in_sizes, int n_in,
                              void* d_out, int out_size, void* d_ws, size_t ws_size,
                              hipStream_t stream)
{
    const float* x      = (const float*)d_in[0];
    const float* qkv_w  = (const float*)d_in[2];
    const float* qkv_b  = (const float*)d_in[3];
    const float* proj_w = (const float*)d_in[4];
    const float* proj_b = (const float*)d_in[5];
    const float* rpb    = (const float*)d_in[6];
    const float* n1g    = (const float*)d_in[7];
    const float* n1b    = (const float*)d_in[8];
    const float* n2g    = (const float*)d_in[9];
    const float* n2b    = (const float*)d_in[10];
    const float* fc1w   = (const float*)d_in[11];
    const float* fc1b   = (const float*)d_in[12];
    const float* fc2w   = (const float*)d_in[13];
    const float* fc2b   = (const float*)d_in[14];

    float* xr = (float*)d_out;                     // d_out doubles as xr residual buffer

    // ---- workspace carve-up ----
    unsigned short* p = (unsigned short*)d_ws;
    unsigned short* Wqh = p; p += 442368;  unsigned short* Wql = p; p += 442368;
    unsigned short* Wph = p; p += 147456;  unsigned short* Wpl = p; p += 147456;
    unsigned short* W1h = p; p += 589824;  unsigned short* W1l = p; p += 589824;
    unsigned short* W2h = p; p += 589824;  unsigned short* W2l = p; p += 589824;
    unsigned short* ABh = p; p += (size_t)TOKENS * CC;
    float* Bias = (float*)p;                       // 196608 f32
    unsigned short* region = (unsigned short*)(Bias + 196608);
    unsigned short* Hbuf = region;

    const size_t FIXED = 27131904;                 // bytes before region
    size_t R = (ws_size > FIXED) ? ws_size - FIXED : 0;
    int gq = 2;                                    // images per qkv chunk
    if (R >= (size_t)8 * 7962624)      gq = 8;
    else if (R >= (size_t)4 * 7962624) gq = 4;
    int gh = 2;                                    // images per MLP chunk
    if (R >= (size_t)8 * TPI * HID * 2)      gh = 8;
    else if (R >= (size_t)4 * TPI * HID * 2) gh = 4;

    unsigned short* QKb = region;
    unsigned short* Vtg = region + (size_t)gq * TPI * 768;   // [384][gq*4096]
    int vstride = gq * NWIN * 64;                  // tokens per d-row (win-padded)

    // 0. tables + weight prep + V pad zeroing
    bias_prep<<<768, 256, 0, stream>>>(rpb, Bias);
    wprep<<<dim3(1152/32, 384/32), 256, 0, stream>>>(qkv_w, Wqh, Wql, 384, 1152);
    wprep<<<dim3(384/32,  384/32), 256, 0, stream>>>(proj_w, Wph, Wpl, 384, 384);
    wprep<<<dim3(1536/32, 384/32), 256, 0, stream>>>(fc1w,  W1h, W1l, 384, 1536);
    wprep<<<dim3(384/32, 1536/32), 256, 0, stream>>>(fc2w,  W2h, W2l, 1536, 384);
    zerofill<<<2048, 256, 0, stream>>>((unsigned int*)Vtg, (long)384 * vstride / 2);

    // 1. LN1 + shift + window partition -> ABh (window-ordered, bf16)
    ln_kernel<true><<<TOKENS, 128, 0, stream>>>(x, n1g, n1b, ABh);

    // 2+3. per-chunk: QKV GEMM -> QKb/Vtg, MFMA attention -> ABh
    for (int c = 0; c < 8 / gq; ++c) {
        size_t off = (size_t)c * gq * TPI;
        int M = gq * TPI;
        dim3 gmm((3 * CC) / 128, M / 128);
        gemm_mfma<EPI_QKV, 4><<<gmm, 256, 0, stream>>>(
            ABh + off * CC, Wqh, Wql, qkv_b, nullptr, nullptr, QKb, Vtg, vstride, M, 3 * CC, CC);
        attn3<<<gq * NWIN * HEADS / 4, 256, 0, stream>>>(
            QKb, Vtg, Bias, ABh, vstride, c * gq * NWIN);
    }

    // 4. proj GEMM + window reverse + roll + residual -> xr (= d_out)   [8-wave: N=384 grid-starved]
    {
        dim3 gmm(CC / 128, TOKENS / 128);
        gemm_mfma<EPI_PROJ, 8><<<gmm, 512, 0, stream>>>(
            ABh, Wph, Wpl, proj_b, x, xr, nullptr, nullptr, 0, TOKENS, CC, CC);
    }

    // 5. LN2 -> ABh
    ln_kernel<false><<<TOKENS, 128, 0, stream>>>(xr, n2g, n2b, ABh);

    // 6+7. per-chunk: fc1+GELU -> Hbuf (bf16), fc2 + residual -> d_out  [fc2 8-wave: grid-starved]
    for (int c = 0; c < 8 / gh; ++c) {
        size_t off = (size_t)c * gh * TPI;
        int M = gh * TPI;
        {
            dim3 gmm(HID / 128, M / 128);
            gemm_mfma<EPI_GELU, 4><<<gmm, 256, 0, stream>>>(
                ABh + off * CC, W1h, W1l, fc1b, nullptr, nullptr, Hbuf, nullptr, 0, M, HID, CC);
        }
        {
            dim3 gmm(CC / 128, M / 128);
            gemm_mfma<EPI_FC2, 8><<<gmm, 512, 0, stream>>>(
                Hbuf, W2h, W2l, fc2b, xr + off * CC, (float*)d_out + off * CC, nullptr, nullptr, 0, M, CC, HID);
        }
    }
}